// Round 4
// baseline (1378.391 us; speedup 1.0000x reference)
//
#include <hip/hip_runtime.h>
#include <hip/hip_bf16.h>
#include <math.h>

typedef short bf16x8 __attribute__((ext_vector_type(8)));
typedef float f32x4 __attribute__((ext_vector_type(4)));

#define DEV __device__ __forceinline__

DEV ushort f2b(float x) {
    unsigned u = __float_as_uint(x);
    u += 0x7fffu + ((u >> 16) & 1u);
    return (ushort)(u >> 16);
}
DEV float b2f(ushort h) { return __uint_as_float(((unsigned)h) << 16); }
DEV float gelu_f(float x) { return 0.5f * x * (1.0f + erff(x * 0.70710678118654752f)); }

// async global->LDS, 16B per lane; LDS dest wave-uniform base (lane*16 added by HW)
DEV void gl2lds16(const void* g, void* l) {
    __builtin_amdgcn_global_load_lds(
        (const __attribute__((address_space(1))) void*)(uintptr_t)g,
        (__attribute__((address_space(3))) void*)(uintptr_t)l, 16, 0, 0);
}

// ---------------------------------------------------------------------------
// Weight transpose + cast:  Wt[n*K + k] = bf16(W[k*N + n])
// ---------------------------------------------------------------------------
__global__ __launch_bounds__(256) void castT_k(const float* __restrict__ W,
                                               ushort* __restrict__ Wt, int K, int N) {
    long i = (long)blockIdx.x * 256 + threadIdx.x;
    if (i < (long)K * N) {
        int k = (int)(i / N), n = (int)(i % N);
        Wt[(long)n * K + k] = f2b(W[i]);
    }
}

// data[:, 2:1026] f32 -> bf16 [50176][1024]
__global__ __launch_bounds__(256) void dcast_k(const float* __restrict__ data,
                                               ushort* __restrict__ out) {
    long i = ((long)blockIdx.x * 256 + threadIdx.x) * 8;
    int r = (int)(i >> 10);
    int c = (int)(i & 1023);
    const float* p = data + (long)r * 1026 + 2 + c;
    float2 f0 = *(const float2*)p;
    float2 f1 = *(const float2*)(p + 2);
    float2 f2 = *(const float2*)(p + 4);
    float2 f3 = *(const float2*)(p + 6);
    int4 pk;
    pk.x = (int)f2b(f0.x) | ((int)f2b(f0.y) << 16);
    pk.y = (int)f2b(f1.x) | ((int)f2b(f1.y) << 16);
    pk.z = (int)f2b(f2.x) | ((int)f2b(f2.y) << 16);
    pk.w = (int)f2b(f3.x) | ((int)f2b(f3.y) << 16);
    *(int4*)(&out[i]) = pk;
}

// ---------------------------------------------------------------------------
// piecewise_index |.| table for d = 0..511
// ---------------------------------------------------------------------------
__global__ void pw_k(int* __restrict__ pw) {
    int d = threadIdx.x;
    int v;
    if (d == 0) v = 0;
    else if (d <= 3) v = 1;
    else {
        float t = logf((float)d / 1.9f) / 1.7917594692280552f * 3.8f;
        int r = (int)rintf(t);
        v = r < 7 ? r : 7;
    }
    pw[d] = v;
}

// ---------------------------------------------------------------------------
// GEMM: C[M x N] = A[M x K] @ B[K x N] (+bias, epilogues).  A bf16 [M][lda],
// B as Bt[N][K] bf16.  BM=BN=128, BK=64, 4 waves (2x2 of 64x64), 16x16x32 MFMA.
// 2-phase double-buffered LDS (64 KB): next-tile global_load_lds issued after
// current tile's first ds_read batch, single barrier per K-step.
// Staging: linear LDS dest, pre-swizzled global source; read slot = g^(row&7).
// Block swizzle: bijective XCD chunking.
// EPI: 0 relu->f32  1 +bias->bf16  2 gelu(hres+x)->f32  3 outF[perm?]+=x
//      4 gelu->bf16  5 tanh->bf16  6 qkv: q,k->outB, v -> vtp[w][h][d][tok64]
// ---------------------------------------------------------------------------
template <int EPI, bool PERMA, bool PERMOUT>
__global__ __launch_bounds__(256) void gemm_k(const ushort* __restrict__ A, long lda,
                                              const ushort* __restrict__ Bt,
                                              const float* __restrict__ bias,
                                              const float* __restrict__ hres,
                                              float* __restrict__ outF,
                                              ushort* __restrict__ outB,
                                              ushort* __restrict__ vtp, int N, int K) {
    __shared__ ushort sh[2][2][128 * 64];
    const int tid = threadIdx.x;
    const int nN = N >> 7;
    // bijective XCD-chunk swizzle (m204)
    int nwg = gridDim.x;
    int xcd = blockIdx.x & 7, lin = blockIdx.x >> 3;
    int q = nwg >> 3, r8 = nwg & 7;
    int swz = (xcd < r8 ? xcd * (q + 1) : r8 * (q + 1) + (xcd - r8) * q) + lin;
    const long m0 = (long)(swz / nN) * 128;
    const int n0 = (swz % nN) * 128;
    const int l = tid & 63, wv = tid >> 6;
    const int wm = (wv >> 1) * 64, wn = (wv & 1) * 64;
    const int rr = l & 15, lg = l >> 4;
    const int srl = l >> 3;        // staging row-in-group 0..7
    const int sg = (l & 7) ^ srl;  // pre-swizzled source granule

    f32x4 acc[4][4];
#pragma unroll
    for (int a = 0; a < 4; ++a)
#pragma unroll
        for (int b = 0; b < 4; ++b) acc[a][b] = (f32x4){0.f, 0.f, 0.f, 0.f};

    auto stage = [&](int buf, int k0) {
#pragma unroll
        for (int c = 0; c < 4; ++c) {
            int row = wv * 32 + c * 8 + srl;
            long arow = m0 + row;
            if (PERMA) {
                int qq = (int)arow / 49;
                int ss = (int)arow - qq * 49;
                arow = (long)ss * 1024 + qq;
            }
            gl2lds16(A + arow * lda + k0 + sg * 8, &sh[buf][0][(wv * 32 + c * 8) * 64]);
            gl2lds16(Bt + (long)(n0 + row) * K + k0 + sg * 8, &sh[buf][1][(wv * 32 + c * 8) * 64]);
        }
    };

    const int nT = K >> 6;
    stage(0, 0);
    __syncthreads();
    int cur = 0;

    for (int t = 0; t < nT; ++t) {
        const ushort* As = &sh[cur][0][0];
        const ushort* Bs = &sh[cur][1][0];
        // kk = 0 fragment reads
        bf16x8 a0[4], b0[4];
#pragma unroll
        for (int mt = 0; mt < 4; ++mt) {
            int row = wm + mt * 16 + rr;
            a0[mt] = *(const bf16x8*)(&As[row * 64 + (lg ^ (row & 7)) * 8]);
        }
#pragma unroll
        for (int nt = 0; nt < 4; ++nt) {
            int row = wn + nt * 16 + rr;
            b0[nt] = *(const bf16x8*)(&Bs[row * 64 + (lg ^ (row & 7)) * 8]);
        }
        // prefetch next K-tile while MFMAs run
        if (t + 1 < nT) stage(cur ^ 1, (t + 1) * 64);
#pragma unroll
        for (int mt = 0; mt < 4; ++mt)
#pragma unroll
            for (int nt = 0; nt < 4; ++nt)
                acc[mt][nt] =
                    __builtin_amdgcn_mfma_f32_16x16x32_bf16(a0[mt], b0[nt], acc[mt][nt], 0, 0, 0);
        // kk = 1
        bf16x8 a1[4], b1[4];
#pragma unroll
        for (int mt = 0; mt < 4; ++mt) {
            int row = wm + mt * 16 + rr;
            a1[mt] = *(const bf16x8*)(&As[row * 64 + ((4 + lg) ^ (row & 7)) * 8]);
        }
#pragma unroll
        for (int nt = 0; nt < 4; ++nt) {
            int row = wn + nt * 16 + rr;
            b1[nt] = *(const bf16x8*)(&Bs[row * 64 + ((4 + lg) ^ (row & 7)) * 8]);
        }
#pragma unroll
        for (int mt = 0; mt < 4; ++mt)
#pragma unroll
            for (int nt = 0; nt < 4; ++nt)
                acc[mt][nt] =
                    __builtin_amdgcn_mfma_f32_16x16x32_bf16(a1[mt], b1[nt], acc[mt][nt], 0, 0, 0);
        __syncthreads();
        cur ^= 1;
    }

#pragma unroll
    for (int mt = 0; mt < 4; ++mt) {
#pragma unroll
        for (int e = 0; e < 4; ++e) {
            long gr = m0 + wm + mt * 16 + lg * 4 + e;
            long orow = gr;
            if (PERMOUT) {
                int qq = (int)gr / 49;
                int ss = (int)gr - qq * 49;
                orow = (long)ss * 1024 + qq;
            }
#pragma unroll
            for (int nt = 0; nt < 4; ++nt) {
                int gc = n0 + wn + nt * 16 + rr;
                float v = acc[mt][nt][e] + bias[gc];
                if (EPI == 0) {
                    outF[gr * N + gc] = fmaxf(v, 0.f);
                } else if (EPI == 1) {
                    outB[gr * N + gc] = f2b(v);
                } else if (EPI == 2) {
                    outF[gr * N + gc] = gelu_f(hres[gr * N + gc] + v);
                } else if (EPI == 3) {
                    outF[orow * N + gc] += v;
                } else if (EPI == 4) {
                    outB[gr * N + gc] = f2b(gelu_f(v));
                } else if (EPI == 5) {
                    outB[gr * N + gc] = f2b(tanhf(v));
                } else {  // EPI 6: qkv split with V^T
                    if (gc < 1024) {
                        outB[gr * N + gc] = f2b(v);
                    } else {
                        int hh = (gc - 1024) >> 6, dd = (gc - 1024) & 63;
                        int ww = (int)(gr / 49);
                        int tt = (int)(gr - (long)ww * 49);
                        vtp[(((long)ww * 8 + hh) * 64 + dd) * 64 + tt] = f2b(v);
                    }
                }
            }
        }
    }
}

// ---------------------------------------------------------------------------
// LayerNorm over rows of 512. 256 thr = 4 waves, one row per wave.
// ---------------------------------------------------------------------------
__global__ __launch_bounds__(256) void ln_k(const float* __restrict__ x,
                                            const float* __restrict__ g,
                                            const float* __restrict__ b,
                                            ushort* __restrict__ outB, float* __restrict__ outF) {
    long row = (long)blockIdx.x * 4 + (threadIdx.x >> 6);
    int l = threadIdx.x & 63;
    const float* xr = x + row * 512 + l * 8;
    float4 v0 = *(const float4*)xr;
    float4 v1 = *(const float4*)(xr + 4);
    float s = v0.x + v0.y + v0.z + v0.w + v1.x + v1.y + v1.z + v1.w;
    float q = v0.x * v0.x + v0.y * v0.y + v0.z * v0.z + v0.w * v0.w + v1.x * v1.x + v1.y * v1.y +
              v1.z * v1.z + v1.w * v1.w;
#pragma unroll
    for (int m = 1; m < 64; m <<= 1) {
        s += __shfl_xor(s, m);
        q += __shfl_xor(q, m);
    }
    float mean = s * (1.f / 512.f);
    float var = q * (1.f / 512.f) - mean * mean;
    float rstd = rsqrtf(var + 1e-5f);
    float4 g0 = *(const float4*)(g + l * 8);
    float4 g1 = *(const float4*)(g + l * 8 + 4);
    float4 b0 = *(const float4*)(b + l * 8);
    float4 b1 = *(const float4*)(b + l * 8 + 4);
    float y[8];
    y[0] = (v0.x - mean) * rstd * g0.x + b0.x;
    y[1] = (v0.y - mean) * rstd * g0.y + b0.y;
    y[2] = (v0.z - mean) * rstd * g0.z + b0.z;
    y[3] = (v0.w - mean) * rstd * g0.w + b0.w;
    y[4] = (v1.x - mean) * rstd * g1.x + b1.x;
    y[5] = (v1.y - mean) * rstd * g1.y + b1.y;
    y[6] = (v1.z - mean) * rstd * g1.z + b1.z;
    y[7] = (v1.w - mean) * rstd * g1.w + b1.w;
    if (outB) {
        int4 pk;
        pk.x = (int)f2b(y[0]) | ((int)f2b(y[1]) << 16);
        pk.y = (int)f2b(y[2]) | ((int)f2b(y[3]) << 16);
        pk.z = (int)f2b(y[4]) | ((int)f2b(y[5]) << 16);
        pk.w = (int)f2b(y[6]) | ((int)f2b(y[7]) << 16);
        *(int4*)(&outB[row * 512 + l * 8]) = pk;
    }
    if (outF) {
        float4 o0 = {y[0], y[1], y[2], y[3]};
        float4 o1 = {y[4], y[5], y[6], y[7]};
        *(float4*)(&outF[row * 512 + l * 8]) = o0;
        *(float4*)(&outF[row * 512 + l * 8 + 4]) = o1;
    }
}

// ---------------------------------------------------------------------------
// Fused per-(window,head) attention. 1 wave/block, 49 tokens padded to 64.
// Q,K fragments direct from qkv; V^T fragments direct from vtp (written
// transposed by the qkv GEMM epilogue; pad token slots 49..63 are GARBAGE
// and masked to zero at load). Only P goes through LDS.
// ---------------------------------------------------------------------------
template <bool BIAS>
__global__ __launch_bounds__(64) void attn_k(const ushort* __restrict__ qkv,
                                             const ushort* __restrict__ vtp,
                                             const float* __restrict__ cdata,
                                             const int* __restrict__ pwt,
                                             const float* __restrict__ btg,
                                             ushort* __restrict__ outb) {
    __shared__ ushort ps[4096];
    __shared__ float cx[64], cy[64], bt[16];
    __shared__ unsigned char pwu[512];

    const int l = threadIdx.x;
    const int w = blockIdx.x >> 3, hh = blockIdx.x & 7;
    const long rowbase = (long)w * 49;
    const ushort* vbase = vtp + ((long)w * 8 + hh) * 4096;
    const int rr = l & 15, lg = l >> 4;

    if (BIAS) {
        if (l < 49) {
            cx[l] = cdata[(rowbase + l) * 1026];
            cy[l] = cdata[(rowbase + l) * 1026 + 1];
        }
        if (l < 15) bt[l] = btg[l * 8 + hh];
        for (int i = l; i < 512; i += 64) pwu[i] = (unsigned char)pwt[i];
    }

    // QK^T: direct global fragment loads
    f32x4 s[4][4];
#pragma unroll
    for (int a = 0; a < 4; ++a)
#pragma unroll
        for (int b = 0; b < 4; ++b) s[a][b] = (f32x4){0.f, 0.f, 0.f, 0.f};

    const bf16x8 zfrag = {0, 0, 0, 0, 0, 0, 0, 0};
#pragma unroll
    for (int kk = 0; kk < 2; ++kk) {
        bf16x8 a[4], b[4];
#pragma unroll
        for (int mt = 0; mt < 4; ++mt) {
            int i = mt * 16 + rr;
            a[mt] = (i < 49) ? *(const bf16x8*)(qkv + (rowbase + i) * 1536 + hh * 64 +
                                                (kk * 4 + lg) * 8)
                             : zfrag;
        }
#pragma unroll
        for (int nt = 0; nt < 4; ++nt) {
            int j = nt * 16 + rr;
            b[nt] = (j < 49) ? *(const bf16x8*)(qkv + (rowbase + j) * 1536 + 512 + hh * 64 +
                                                (kk * 4 + lg) * 8)
                             : zfrag;
        }
#pragma unroll
        for (int mt = 0; mt < 4; ++mt)
#pragma unroll
            for (int nt = 0; nt < 4; ++nt)
                s[mt][nt] = __builtin_amdgcn_mfma_f32_16x16x32_bf16(a[mt], b[nt], s[mt][nt], 0, 0, 0);
    }
    __syncthreads();

    float rl[4][4];
#pragma unroll
    for (int mt = 0; mt < 4; ++mt) {
#pragma unroll
        for (int e = 0; e < 4; ++e) {
            int i = mt * 16 + lg * 4 + e;
            float x[4];
#pragma unroll
            for (int nt = 0; nt < 4; ++nt) {
                int j = nt * 16 + rr;
                float v = s[mt][nt][e] * 0.125f;
                if (j >= 49) {
                    v = -1e30f;
                } else if (BIAS) {
                    if (i < 49) {
                        int dx = (int)fabsf(cx[i] - cx[j]);
                        int dy = (int)fabsf(cy[i] - cy[j]);
                        v += bt[pwu[dx] + pwu[dy]];
                    }
                }
                x[nt] = v;
            }
            float m = fmaxf(fmaxf(x[0], x[1]), fmaxf(x[2], x[3]));
#pragma unroll
            for (int msk = 1; msk < 16; msk <<= 1) m = fmaxf(m, __shfl_xor(m, msk));
            float sum = 0.f;
#pragma unroll
            for (int nt = 0; nt < 4; ++nt) {
                float p = __expf(x[nt] - m);
                x[nt] = p;
                sum += p;
            }
#pragma unroll
            for (int msk = 1; msk < 16; msk <<= 1) sum += __shfl_xor(sum, msk);
            rl[mt][e] = 1.f / sum;
#pragma unroll
            for (int nt = 0; nt < 4; ++nt) {
                int j = nt * 16 + rr;
                ps[i * 64 + (((j >> 3) ^ (i & 7)) * 8) + (j & 7)] = f2b(x[nt]);
            }
        }
    }
    __syncthreads();

    f32x4 o[4][4];
#pragma unroll
    for (int a = 0; a < 4; ++a)
#pragma unroll
        for (int b = 0; b < 4; ++b) o[a][b] = (f32x4){0.f, 0.f, 0.f, 0.f};

#pragma unroll
    for (int kk = 0; kk < 2; ++kk) {
        bf16x8 a[4], b[4];
        const int ts = (kk * 4 + lg) * 8;  // first token slot in this V granule
#pragma unroll
        for (int mt = 0; mt < 4; ++mt) {
            int i = mt * 16 + rr;
            int slot = (kk * 4 + lg) ^ (i & 7);
            a[mt] = *(const bf16x8*)(&ps[i * 64 + slot * 8]);
        }
#pragma unroll
        for (int nt = 0; nt < 4; ++nt) {
            int d = nt * 16 + rr;
            bf16x8 v = *(const bf16x8*)(vbase + d * 64 + (kk * 4 + lg) * 8);
            // mask pad tokens (slots >= 49 hold garbage; 0*NaN would poison MFMA)
            if (ts >= 56) {
                v = zfrag;
            } else if (ts == 48) {
#pragma unroll
                for (int ii = 1; ii < 8; ++ii) v[ii] = 0;
            }
            b[nt] = v;
        }
#pragma unroll
        for (int mt = 0; mt < 4; ++mt)
#pragma unroll
            for (int nt = 0; nt < 4; ++nt)
                o[mt][nt] = __builtin_amdgcn_mfma_f32_16x16x32_bf16(a[mt], b[nt], o[mt][nt], 0, 0, 0);
    }

#pragma unroll
    for (int mt = 0; mt < 4; ++mt) {
#pragma unroll
        for (int e = 0; e < 4; ++e) {
            int i = mt * 16 + lg * 4 + e;
            if (i < 49) {
#pragma unroll
                for (int nt = 0; nt < 4; ++nt) {
                    int col = hh * 64 + nt * 16 + rr;
                    outb[(rowbase + i) * 512 + col] = f2b(o[mt][nt][e] * rl[mt][e]);
                }
            }
        }
    }
}

// ---------------------------------------------------------------------------
// A[r] = tanh_t[r,:256] . ap_w2 + ap_b2     (one wave per row)
// ---------------------------------------------------------------------------
__global__ __launch_bounds__(256) void ap2_k(const ushort* __restrict__ tb,
                                             const float* __restrict__ w2,
                                             const float* __restrict__ b2,
                                             float* __restrict__ Avec) {
    long row = (long)blockIdx.x * 4 + (threadIdx.x >> 6);
    int l = threadIdx.x & 63;
    ushort4 u = *(const ushort4*)(tb + row * 256 + l * 4);
    float4 wv = *(const float4*)(w2 + l * 4);
    float s = b2f(u.x) * wv.x + b2f(u.y) * wv.y + b2f(u.z) * wv.z + b2f(u.w) * wv.w;
#pragma unroll
    for (int m = 1; m < 64; m <<= 1) s += __shfl_xor(s, m);
    if (l == 0) Avec[row] = s + b2[0];
}

__global__ __launch_bounds__(1024) void smprep_k(const float* __restrict__ A, int M,
                                                 float* __restrict__ sc) {
    __shared__ float red[1024];
    int t = threadIdx.x;
    float m = -3.4e38f;
    for (int i = t; i < M; i += 1024) m = fmaxf(m, A[i]);
    red[t] = m;
    __syncthreads();
    for (int o = 512; o > 0; o >>= 1) {
        if (t < o) red[t] = fmaxf(red[t], red[t + o]);
        __syncthreads();
    }
    float mx = red[0];
    __syncthreads();
    float s = 0.f;
    for (int i = t; i < M; i += 1024) s += __expf(A[i] - mx);
    red[t] = s;
    __syncthreads();
    for (int o = 512; o > 0; o >>= 1) {
        if (t < o) red[t] += red[t + o];
        __syncthreads();
    }
    if (t == 0) {
        sc[0] = mx;
        sc[1] = red[0];
    }
}

__global__ __launch_bounds__(256) void pool1_k(const float* __restrict__ Avec,
                                               const float* __restrict__ sc,
                                               const float* __restrict__ feat,
                                               float* __restrict__ partial) {
    int t = threadIdx.x;
    long base = (long)blockIdx.x * 256;
    float mx = sc[0], rd = 1.f / sc[1];
    float a0 = 0.f, a1 = 0.f;
    for (int i = 0; i < 256; ++i) {
        long tok = base + i;
        float wt = __expf(Avec[tok] - mx) * rd;
        a0 += wt * feat[tok * 512 + t];
        a1 += wt * feat[tok * 512 + t + 256];
    }
    partial[(long)blockIdx.x * 512 + t] = a0;
    partial[(long)blockIdx.x * 512 + t + 256] = a1;
}

__global__ __launch_bounds__(512) void final_k(const float* __restrict__ partial, int NP,
                                               const float* __restrict__ fc2w,
                                               const float* __restrict__ fc2b,
                                               float* __restrict__ out) {
    __shared__ float pooled[512];
    __shared__ float lgs[4];
    int t = threadIdx.x;
    float s = 0.f;
    for (int b = 0; b < NP; ++b) s += partial[(long)b * 512 + t];
    pooled[t] = s;
    __syncthreads();
    if (t < 4) {
        float x = fc2b[t];
        for (int c = 0; c < 512; ++c) x += pooled[c] * fc2w[c * 4 + t];
        lgs[t] = x;
    }
    __syncthreads();
    if (t == 0) {
        float hz[4];
        for (int i = 0; i < 4; ++i) hz[i] = 1.f / (1.f + __expf(-lgs[i]));
        for (int i = 0; i < 4; ++i) out[i] = hz[i];
        float cp = 1.f;
        for (int i = 0; i < 4; ++i) {
            cp *= (1.f - hz[i]);
            out[4 + i] = cp;
        }
        int best = 0;
        for (int i = 1; i < 4; ++i)
            if (lgs[i] > lgs[best]) best = i;
        out[8] = (float)best;
    }
}

// ---------------------------------------------------------------------------
extern "C" void kernel_launch(void* const* d_in, const int* in_sizes, int n_in, void* d_out,
                              int out_size, void* d_ws, size_t ws_size, hipStream_t stream) {
    const float* data = (const float*)d_in[0];
    const float* fc1_w = (const float*)d_in[1];
    const float* fc1_b = (const float*)d_in[2];
    const float* ln1_g = (const float*)d_in[3];
    const float* ln1_b = (const float*)d_in[4];
    const float* wa_qkv_w = (const float*)d_in[5];
    const float* wa_qkv_b = (const float*)d_in[6];
    const float* wa_bt = (const float*)d_in[7];
    const float* wa_proj_w = (const float*)d_in[8];
    const float* wa_proj_b = (const float*)d_in[9];
    const float* n1_g = (const float*)d_in[10];
    const float* n1_b = (const float*)d_in[11];
    const float* sa_qkv_w = (const float*)d_in[12];
    const float* sa_qkv_b = (const float*)d_in[13];
    const float* sa_proj_w = (const float*)d_in[14];
    const float* sa_proj_b = (const float*)d_in[15];
    const float* n2_g = (const float*)d_in[16];
    const float* n2_b = (const float*)d_in[17];
    const float* mlp_w1 = (const float*)d_in[18];
    const float* mlp_b1 = (const float*)d_in[19];
    const float* mlp_w2 = (const float*)d_in[20];
    const float* mlp_b2 = (const float*)d_in[21];
    const float* n3_g = (const float*)d_in[22];
    const float* n3_b = (const float*)d_in[23];
    const float* ap_w1 = (const float*)d_in[24];
    const float* ap_b1 = (const float*)d_in[25];
    const float* ap_w2 = (const float*)d_in[26];
    const float* ap_b2 = (const float*)d_in[27];
    const float* fc2_w = (const float*)d_in[28];
    const float* fc2_b = (const float*)d_in[29];

    const int M = 50176;  // tokens
    const int nM = M / 128;

    char* ws = (char*)d_ws;
    size_t off = 0;
    auto alloc = [&](size_t bytes) {
        size_t p = off;
        off = (off + bytes + 255) & ~(size_t)255;
        return (void*)(ws + p);
    };

    ushort* fc1T = (ushort*)alloc((size_t)512 * 1024 * 2);
    ushort* waqkvT = (ushort*)alloc((size_t)1536 * 512 * 2);
    ushort* waprojT = (ushort*)alloc((size_t)512 * 512 * 2);
    ushort* saqkvT = (ushort*)alloc((size_t)1536 * 512 * 2);
    ushort* saprojT = (ushort*)alloc((size_t)512 * 512 * 2);
    ushort* mlp1T = (ushort*)alloc((size_t)512 * 512 * 2);
    ushort* mlp2T = (ushort*)alloc((size_t)512 * 512 * 2);
    ushort* ap1T = (ushort*)alloc((size_t)256 * 512 * 2);
    int* pwtab = (int*)alloc(512 * 4);
    float* sc = (float*)alloc(64);
    float* Avec = (float*)alloc((size_t)M * 4);
    float* partial = (float*)alloc((size_t)196 * 512 * 4);
    float* hb = (float*)alloc((size_t)M * 512 * 4);
    float* fb = (float*)alloc((size_t)M * 512 * 4);
    ushort* lnb = (ushort*)alloc((size_t)M * 512 * 2);
    ushort* attnout = (ushort*)alloc((size_t)M * 512 * 2);
    ushort* qkvb = (ushort*)alloc((size_t)M * 1536 * 2);
    ushort* dataB = qkvb;            // [M][1024] bf16, dead once WA qkv runs
    ushort* tb = qkvb;               // tanh output (M x 256), after SA attn done
    ushort* wavT = (ushort*)fb;      // V^T for WA: fb not yet written (67 MB < 103 MB)
    ushort* savT = (ushort*)hb;      // V^T for SA: h dead after WA proj

    // weight transposes + casts + tables
    castT_k<<<(512 * 1024 + 255) / 256, 256, 0, stream>>>(fc1_w, fc1T, 1024, 512);
    castT_k<<<(512 * 1536 + 255) / 256, 256, 0, stream>>>(wa_qkv_w, waqkvT, 512, 1536);
    castT_k<<<(512 * 512 + 255) / 256, 256, 0, stream>>>(wa_proj_w, waprojT, 512, 512);
    castT_k<<<(512 * 1536 + 255) / 256, 256, 0, stream>>>(sa_qkv_w, saqkvT, 512, 1536);
    castT_k<<<(512 * 512 + 255) / 256, 256, 0, stream>>>(sa_proj_w, saprojT, 512, 512);
    castT_k<<<(512 * 512 + 255) / 256, 256, 0, stream>>>(mlp_w1, mlp1T, 512, 512);
    castT_k<<<(512 * 512 + 255) / 256, 256, 0, stream>>>(mlp_w2, mlp2T, 512, 512);
    castT_k<<<(256 * 512 + 255) / 256, 256, 0, stream>>>(ap_w1, ap1T, 512, 256);
    pw_k<<<1, 512, 0, stream>>>(pwtab);
    dcast_k<<<25088, 256, 0, stream>>>(data, dataB);

    // fc1 + relu -> h
    gemm_k<0, false, false><<<nM * 4, 256, 0, stream>>>(dataB, 1024, fc1T, fc1_b, nullptr, hb,
                                                        nullptr, nullptr, 512, 1024);
    // ln1(h) -> lnb
    ln_k<<<M / 4, 256, 0, stream>>>(hb, ln1_g, ln1_b, lnb, nullptr);
    // WA qkv (V written transposed into wavT)
    gemm_k<6, false, false><<<nM * 12, 256, 0, stream>>>(lnb, 512, waqkvT, wa_qkv_b, nullptr,
                                                         nullptr, qkvb, wavT, 1536, 512);
    // WA attention (with bias)
    attn_k<true><<<8192, 64, 0, stream>>>(qkvb, wavT, data, pwtab, wa_bt, attnout);
    // WA proj: f = gelu(h + out)
    gemm_k<2, false, false><<<nM * 4, 256, 0, stream>>>(attnout, 512, waprojT, wa_proj_b, hb, fb,
                                                        nullptr, nullptr, 512, 512);
    // norm1(f) -> lnb
    ln_k<<<M / 4, 256, 0, stream>>>(fb, n1_g, n1_b, lnb, nullptr);
    // SA qkv (permuted gather of A rows; V^T into savT)
    gemm_k<6, true, false><<<nM * 12, 256, 0, stream>>>(lnb, 512, saqkvT, sa_qkv_b, nullptr,
                                                        nullptr, qkvb, savT, 1536, 512);
    // SA attention (no bias)
    attn_k<false><<<8192, 64, 0, stream>>>(qkvb, savT, nullptr, nullptr, nullptr, attnout);
    // SA proj: f[perm] += out
    gemm_k<3, false, true><<<nM * 4, 256, 0, stream>>>(attnout, 512, saprojT, sa_proj_b, nullptr,
                                                       fb, nullptr, nullptr, 512, 512);
    // norm2(f) -> lnb
    ln_k<<<M / 4, 256, 0, stream>>>(fb, n2_g, n2_b, lnb, nullptr);
    // mlp1: hidden = gelu(lnb @ w1 + b1) -> attnout
    gemm_k<4, false, false><<<nM * 4, 256, 0, stream>>>(lnb, 512, mlp1T, mlp_b1, nullptr, nullptr,
                                                        attnout, nullptr, 512, 512);
    // mlp2: f += hidden @ w2 + b2
    gemm_k<3, false, false><<<nM * 4, 256, 0, stream>>>(attnout, 512, mlp2T, mlp_b2, nullptr, fb,
                                                        nullptr, nullptr, 512, 512);
    // norm3(f) -> feat (f32 into hb) + lnb
    ln_k<<<M / 4, 256, 0, stream>>>(fb, n3_g, n3_b, lnb, hb);
    // ap1: t = tanh(lnb @ ap_w1 + b1) -> tb
    gemm_k<5, false, false><<<nM * 2, 256, 0, stream>>>(lnb, 512, ap1T, ap_b1, nullptr, nullptr,
                                                        tb, nullptr, 256, 512);
    // A = t @ ap_w2 + b2
    ap2_k<<<M / 4, 256, 0, stream>>>(tb, ap_w2, ap_b2, Avec);
    // softmax prep
    smprep_k<<<1, 1024, 0, stream>>>(Avec, M, sc);
    // pooled partials
    pool1_k<<<196, 256, 0, stream>>>(Avec, sc, hb, partial);
    // final head
    final_k<<<1, 512, 0, stream>>>(partial, 196, fc2_w, fc2_b, (float*)d_out);
}

// Round 5
// 1242.340 us; speedup vs baseline: 1.1095x; 1.1095x over previous
//
#include <hip/hip_runtime.h>
#include <hip/hip_bf16.h>
#include <math.h>

typedef short bf16x8 __attribute__((ext_vector_type(8)));
typedef float f32x4 __attribute__((ext_vector_type(4)));

#define DEV __device__ __forceinline__

DEV ushort f2b(float x) {
    unsigned u = __float_as_uint(x);
    u += 0x7fffu + ((u >> 16) & 1u);
    return (ushort)(u >> 16);
}
DEV float b2f(ushort h) { return __uint_as_float(((unsigned)h) << 16); }
DEV float gelu_f(float x) { return 0.5f * x * (1.0f + erff(x * 0.70710678118654752f)); }

// async global->LDS, 16B per lane; LDS dest wave-uniform base (lane*16 added by HW)
DEV void gl2lds16(const void* g, void* l) {
    __builtin_amdgcn_global_load_lds(
        (const __attribute__((address_space(1))) void*)(uintptr_t)g,
        (__attribute__((address_space(3))) void*)(uintptr_t)l, 16, 0, 0);
}

#define BAR() __builtin_amdgcn_s_barrier()

// ---------------------------------------------------------------------------
// Weight transpose + cast:  Wt[n*K + k] = bf16(W[k*N + n])
// ---------------------------------------------------------------------------
__global__ __launch_bounds__(256) void castT_k(const float* __restrict__ W,
                                               ushort* __restrict__ Wt, int K, int N) {
    long i = (long)blockIdx.x * 256 + threadIdx.x;
    if (i < (long)K * N) {
        int k = (int)(i / N), n = (int)(i % N);
        Wt[(long)n * K + k] = f2b(W[i]);
    }
}

// data[:, 2:1026] f32 -> bf16 [50176][1024]
__global__ __launch_bounds__(256) void dcast_k(const float* __restrict__ data,
                                               ushort* __restrict__ out) {
    long i = ((long)blockIdx.x * 256 + threadIdx.x) * 8;
    int r = (int)(i >> 10);
    int c = (int)(i & 1023);
    const float* p = data + (long)r * 1026 + 2 + c;
    float2 f0 = *(const float2*)p;
    float2 f1 = *(const float2*)(p + 2);
    float2 f2 = *(const float2*)(p + 4);
    float2 f3 = *(const float2*)(p + 6);
    int4 pk;
    pk.x = (int)f2b(f0.x) | ((int)f2b(f0.y) << 16);
    pk.y = (int)f2b(f1.x) | ((int)f2b(f1.y) << 16);
    pk.z = (int)f2b(f2.x) | ((int)f2b(f2.y) << 16);
    pk.w = (int)f2b(f3.x) | ((int)f2b(f3.y) << 16);
    *(int4*)(&out[i]) = pk;
}

// ---------------------------------------------------------------------------
// piecewise_index |.| table for d = 0..511
// ---------------------------------------------------------------------------
__global__ void pw_k(int* __restrict__ pw) {
    int d = threadIdx.x;
    int v;
    if (d == 0) v = 0;
    else if (d <= 3) v = 1;
    else {
        float t = logf((float)d / 1.9f) / 1.7917594692280552f * 3.8f;
        int r = (int)rintf(t);
        v = r < 7 ? r : 7;
    }
    pw[d] = v;
}

// ---------------------------------------------------------------------------
// GEMM: C[M x N] = A[M x K] @ B[K x N] (+bias, epilogues).  A bf16 [M][lda],
// B as Bt[N][K] bf16.  BM=BN=128, BK=32, 4 waves (2x2 of 64x64), 16x16x32 MFMA.
// Double-buffered LDS kept at 32 KB total (5 blocks/CU) via BK=32.
// Counted-vmcnt pipeline: next tile's 4 global_load_lds stay IN FLIGHT across
// the barriers (s_waitcnt vmcnt(4)); only the current buffer's loads drain.
// Staging: linear LDS dest, pre-swizzled source granule tg=(tid&3)^((tid>>3)&3);
// read slot = lg ^ ((row>>1)&3)  -> 2-way max bank aliasing (free).
// Block swizzle: bijective XCD chunking.
// EPI: 0 relu->f32  1 +bias->bf16  2 gelu(hres+x)->f32  3 outF[perm?]+=x
//      4 gelu->bf16  5 tanh->bf16
// ---------------------------------------------------------------------------
template <int EPI, bool PERMA, bool PERMOUT>
__global__ __launch_bounds__(256) void gemm_k(const ushort* __restrict__ A, long lda,
                                              const ushort* __restrict__ Bt,
                                              const float* __restrict__ bias,
                                              const float* __restrict__ hres,
                                              float* __restrict__ outF,
                                              ushort* __restrict__ outB, int N, int K) {
    __shared__ ushort sh[2][2][128 * 32];  // 32 KB total
    const int tid = threadIdx.x;
    const int nN = N >> 7;
    // bijective XCD-chunk swizzle (m204)
    int nwg = gridDim.x;
    int xcd = blockIdx.x & 7, lin = blockIdx.x >> 3;
    int q = nwg >> 3, r8 = nwg & 7;
    int swz = (xcd < r8 ? xcd * (q + 1) : r8 * (q + 1) + (xcd - r8) * q) + lin;
    const long m0 = (long)(swz / nN) * 128;
    const int n0 = (swz % nN) * 128;
    const int l = tid & 63, wv = tid >> 6;
    const int wm = (wv >> 1) * 64, wn = (wv & 1) * 64;
    const int rr = l & 15, lg = l >> 4;
    const int trow = tid >> 2;                       // row within 64-row chunk
    const int tg = (tid & 3) ^ ((tid >> 3) & 3);     // pre-swizzled source granule

    f32x4 acc[4][4];
#pragma unroll
    for (int a = 0; a < 4; ++a)
#pragma unroll
        for (int b = 0; b < 4; ++b) acc[a][b] = (f32x4){0.f, 0.f, 0.f, 0.f};

    auto stage = [&](int buf, int k0) {
#pragma unroll
        for (int c = 0; c < 2; ++c) {
            int row = c * 64 + trow;
            long arow = m0 + row;
            if (PERMA) {
                int qq = (int)arow / 49;
                int ss = (int)arow - qq * 49;
                arow = (long)ss * 1024 + qq;
            }
            gl2lds16(A + arow * lda + k0 + tg * 8, &sh[buf][0][c * 2048 + wv * 512]);
        }
#pragma unroll
        for (int c = 0; c < 2; ++c) {
            int row = c * 64 + trow;
            gl2lds16(Bt + (long)(n0 + row) * K + k0 + tg * 8, &sh[buf][1][c * 2048 + wv * 512]);
        }
    };

    const int nT = K >> 5;
    stage(0, 0);
    asm volatile("s_waitcnt vmcnt(0)" ::: "memory");
    BAR();
    int cur = 0;

    for (int t = 0; t < nT; ++t) {
        if (t + 1 < nT) {
            stage(cur ^ 1, (t + 1) * 32);  // 4 loads issued, stay in flight
            asm volatile("s_waitcnt vmcnt(4)" ::: "memory");  // drain current buf only
        } else {
            asm volatile("s_waitcnt vmcnt(0)" ::: "memory");
        }
        BAR();  // all waves: current buffer fully landed
        bf16x8 a[4], b[4];
#pragma unroll
        for (int mt = 0; mt < 4; ++mt) {
            int row = wm + mt * 16 + rr;
            int slot = lg ^ ((row >> 1) & 3);
            a[mt] = *(const bf16x8*)(&sh[cur][0][row * 32 + slot * 8]);
        }
#pragma unroll
        for (int nt = 0; nt < 4; ++nt) {
            int row = wn + nt * 16 + rr;
            int slot = lg ^ ((row >> 1) & 3);
            b[nt] = *(const bf16x8*)(&sh[cur][1][row * 32 + slot * 8]);
        }
#pragma unroll
        for (int mt = 0; mt < 4; ++mt)
#pragma unroll
            for (int nt = 0; nt < 4; ++nt)
                acc[mt][nt] =
                    __builtin_amdgcn_mfma_f32_16x16x32_bf16(a[mt], b[nt], acc[mt][nt], 0, 0, 0);
        BAR();  // reads of cur done in all waves before next restage
        cur ^= 1;
    }

#pragma unroll
    for (int mt = 0; mt < 4; ++mt) {
#pragma unroll
        for (int e = 0; e < 4; ++e) {
            long gr = m0 + wm + mt * 16 + lg * 4 + e;
            long orow = gr;
            if (PERMOUT) {
                int qq = (int)gr / 49;
                int ss = (int)gr - qq * 49;
                orow = (long)ss * 1024 + qq;
            }
#pragma unroll
            for (int nt = 0; nt < 4; ++nt) {
                int gc = n0 + wn + nt * 16 + rr;
                float v = acc[mt][nt][e] + bias[gc];
                if (EPI == 0) {
                    outF[gr * N + gc] = fmaxf(v, 0.f);
                } else if (EPI == 1) {
                    outB[gr * N + gc] = f2b(v);
                } else if (EPI == 2) {
                    outF[gr * N + gc] = gelu_f(hres[gr * N + gc] + v);
                } else if (EPI == 3) {
                    outF[orow * N + gc] += v;
                } else if (EPI == 4) {
                    outB[gr * N + gc] = f2b(gelu_f(v));
                } else {
                    outB[gr * N + gc] = f2b(tanhf(v));
                }
            }
        }
    }
}

// ---------------------------------------------------------------------------
// V transpose: vtp[(w*8+h)*4096 + d*64 + t] = V[w,t,h,d], zero-padded t>=49.
// One block per (w,h), 64 threads. Coalesced read, LDS granule-XOR transpose,
// coalesced 128B/wave writes.
// ---------------------------------------------------------------------------
__global__ __launch_bounds__(64) void vtt_k(const ushort* __restrict__ qkv,
                                            ushort* __restrict__ vtp) {
    __shared__ ushort lds[49 * 64];
    const int l = threadIdx.x;
    const int w = blockIdx.x >> 3, hh = blockIdx.x & 7;
    const long rowbase = (long)w * 49;
    for (int idx = l; idx < 49 * 8; idx += 64) {
        int r = idx >> 3, g = idx & 7;
        int4 v = *(const int4*)(qkv + (rowbase + r) * 1536 + 1024 + hh * 64 + g * 8);
        *(int4*)(&lds[r * 64 + ((g ^ (r & 7)) * 8)]) = v;
    }
    __syncthreads();
    ushort* outb = vtp + ((long)w * 8 + hh) * 4096;
#pragma unroll 8
    for (int d = 0; d < 64; ++d) {
        ushort v = 0;
        if (l < 49) v = lds[l * 64 + (((d >> 3) ^ (l & 7)) * 8) + (d & 7)];
        outb[d * 64 + l] = v;
    }
}

// ---------------------------------------------------------------------------
// LayerNorm over rows of 512. 256 thr = 4 waves, one row per wave.
// ---------------------------------------------------------------------------
__global__ __launch_bounds__(256) void ln_k(const float* __restrict__ x,
                                            const float* __restrict__ g,
                                            const float* __restrict__ b,
                                            ushort* __restrict__ outB, float* __restrict__ outF) {
    long row = (long)blockIdx.x * 4 + (threadIdx.x >> 6);
    int l = threadIdx.x & 63;
    const float* xr = x + row * 512 + l * 8;
    float4 v0 = *(const float4*)xr;
    float4 v1 = *(const float4*)(xr + 4);
    float s = v0.x + v0.y + v0.z + v0.w + v1.x + v1.y + v1.z + v1.w;
    float q = v0.x * v0.x + v0.y * v0.y + v0.z * v0.z + v0.w * v0.w + v1.x * v1.x + v1.y * v1.y +
              v1.z * v1.z + v1.w * v1.w;
#pragma unroll
    for (int m = 1; m < 64; m <<= 1) {
        s += __shfl_xor(s, m);
        q += __shfl_xor(q, m);
    }
    float mean = s * (1.f / 512.f);
    float var = q * (1.f / 512.f) - mean * mean;
    float rstd = rsqrtf(var + 1e-5f);
    float4 g0 = *(const float4*)(g + l * 8);
    float4 g1 = *(const float4*)(g + l * 8 + 4);
    float4 b0 = *(const float4*)(b + l * 8);
    float4 b1 = *(const float4*)(b + l * 8 + 4);
    float y[8];
    y[0] = (v0.x - mean) * rstd * g0.x + b0.x;
    y[1] = (v0.y - mean) * rstd * g0.y + b0.y;
    y[2] = (v0.z - mean) * rstd * g0.z + b0.z;
    y[3] = (v0.w - mean) * rstd * g0.w + b0.w;
    y[4] = (v1.x - mean) * rstd * g1.x + b1.x;
    y[5] = (v1.y - mean) * rstd * g1.y + b1.y;
    y[6] = (v1.z - mean) * rstd * g1.z + b1.z;
    y[7] = (v1.w - mean) * rstd * g1.w + b1.w;
    if (outB) {
        int4 pk;
        pk.x = (int)f2b(y[0]) | ((int)f2b(y[1]) << 16);
        pk.y = (int)f2b(y[2]) | ((int)f2b(y[3]) << 16);
        pk.z = (int)f2b(y[4]) | ((int)f2b(y[5]) << 16);
        pk.w = (int)f2b(y[6]) | ((int)f2b(y[7]) << 16);
        *(int4*)(&outB[row * 512 + l * 8]) = pk;
    }
    if (outF) {
        float4 o0 = {y[0], y[1], y[2], y[3]};
        float4 o1 = {y[4], y[5], y[6], y[7]};
        *(float4*)(&outF[row * 512 + l * 8]) = o0;
        *(float4*)(&outF[row * 512 + l * 8 + 4]) = o1;
    }
}

// ---------------------------------------------------------------------------
// Fused per-(window,head) attention. 1 wave/block, 49 tokens padded to 64.
// Q,K fragments direct from qkv; V^T fragments direct from vtp (zero-padded
// by vtt_k). Only P goes through LDS. Softmax reductions batched across the
// 16 rows per lane for ILP (4 shfl rounds, not 16x8 serial shfls).
// ---------------------------------------------------------------------------
template <bool BIAS>
__global__ __launch_bounds__(64) void attn_k(const ushort* __restrict__ qkv,
                                             const ushort* __restrict__ vtp,
                                             const float* __restrict__ cdata,
                                             const int* __restrict__ pwt,
                                             const float* __restrict__ btg,
                                             ushort* __restrict__ outb) {
    __shared__ ushort ps[4096];
    __shared__ float cx[64], cy[64], bt[16];
    __shared__ unsigned char pwu[512];

    const int l = threadIdx.x;
    const int w = blockIdx.x >> 3, hh = blockIdx.x & 7;
    const long rowbase = (long)w * 49;
    const ushort* vbase = vtp + ((long)w * 8 + hh) * 4096;
    const int rr = l & 15, lg = l >> 4;

    if (BIAS) {
        if (l < 49) {
            cx[l] = cdata[(rowbase + l) * 1026];
            cy[l] = cdata[(rowbase + l) * 1026 + 1];
        }
        if (l < 15) bt[l] = btg[l * 8 + hh];
        for (int i = l; i < 512; i += 64) pwu[i] = (unsigned char)pwt[i];
    }

    // QK^T: direct global fragment loads
    f32x4 s[4][4];
#pragma unroll
    for (int a = 0; a < 4; ++a)
#pragma unroll
        for (int b = 0; b < 4; ++b) s[a][b] = (f32x4){0.f, 0.f, 0.f, 0.f};

    const bf16x8 zfrag = {0, 0, 0, 0, 0, 0, 0, 0};
#pragma unroll
    for (int kk = 0; kk < 2; ++kk) {
        bf16x8 a[4], b[4];
#pragma unroll
        for (int mt = 0; mt < 4; ++mt) {
            int i = mt * 16 + rr;
            a[mt] = (i < 49) ? *(const bf16x8*)(qkv + (rowbase + i) * 1536 + hh * 64 +
                                                (kk * 4 + lg) * 8)
                             : zfrag;
        }
#pragma unroll
        for (int nt = 0; nt < 4; ++nt) {
            int j = nt * 16 + rr;
            b[nt] = (j < 49) ? *(const bf16x8*)(qkv + (rowbase + j) * 1536 + 512 + hh * 64 +
                                                (kk * 4 + lg) * 8)
                             : zfrag;
        }
#pragma unroll
        for (int mt = 0; mt < 4; ++mt)
#pragma unroll
            for (int nt = 0; nt < 4; ++nt)
                s[mt][nt] = __builtin_amdgcn_mfma_f32_16x16x32_bf16(a[mt], b[nt], s[mt][nt], 0, 0, 0);
    }
    __syncthreads();

    // scale + bias + padding mask, in place; per-row local max
    float mrow[16], srow[16];
#pragma unroll
    for (int mt = 0; mt < 4; ++mt) {
#pragma unroll
        for (int e = 0; e < 4; ++e) {
            int i = mt * 16 + lg * 4 + e;
            float mloc = -1e30f;
#pragma unroll
            for (int nt = 0; nt < 4; ++nt) {
                int j = nt * 16 + rr;
                float v = s[mt][nt][e] * 0.125f;
                if (j >= 49) {
                    v = -1e30f;
                } else if (BIAS) {
                    if (i < 49) {
                        int dx = (int)fabsf(cx[i] - cx[j]);
                        int dy = (int)fabsf(cy[i] - cy[j]);
                        v += bt[pwu[dx] + pwu[dy]];
                    }
                }
                s[mt][nt][e] = v;
                mloc = fmaxf(mloc, v);
            }
            mrow[mt * 4 + e] = mloc;
        }
    }
    // batched max reduce across the 16 rr lanes (16 independent rows per round)
#pragma unroll
    for (int msk = 1; msk < 16; msk <<= 1)
#pragma unroll
        for (int r = 0; r < 16; ++r) mrow[r] = fmaxf(mrow[r], __shfl_xor(mrow[r], msk));
    // exp + local sum + P write
#pragma unroll
    for (int mt = 0; mt < 4; ++mt) {
#pragma unroll
        for (int e = 0; e < 4; ++e) {
            int r = mt * 4 + e;
            int i = mt * 16 + lg * 4 + e;
            float sm = 0.f;
#pragma unroll
            for (int nt = 0; nt < 4; ++nt) {
                int j = nt * 16 + rr;
                float p = __expf(s[mt][nt][e] - mrow[r]);
                sm += p;
                ps[i * 64 + (((j >> 3) ^ (i & 7)) * 8) + (j & 7)] = f2b(p);
            }
            srow[r] = sm;
        }
    }
#pragma unroll
    for (int msk = 1; msk < 16; msk <<= 1)
#pragma unroll
        for (int r = 0; r < 16; ++r) srow[r] += __shfl_xor(srow[r], msk);
#pragma unroll
    for (int r = 0; r < 16; ++r) srow[r] = 1.f / srow[r];
    __syncthreads();

    f32x4 o[4][4];
#pragma unroll
    for (int a = 0; a < 4; ++a)
#pragma unroll
        for (int b = 0; b < 4; ++b) o[a][b] = (f32x4){0.f, 0.f, 0.f, 0.f};

#pragma unroll
    for (int kk = 0; kk < 2; ++kk) {
        bf16x8 a[4], b[4];
#pragma unroll
        for (int mt = 0; mt < 4; ++mt) {
            int i = mt * 16 + rr;
            int slot = (kk * 4 + lg) ^ (i & 7);
            a[mt] = *(const bf16x8*)(&ps[i * 64 + slot * 8]);
        }
#pragma unroll
        for (int nt = 0; nt < 4; ++nt) {
            int d = nt * 16 + rr;
            b[nt] = *(const bf16x8*)(vbase + d * 64 + (kk * 4 + lg) * 8);
        }
#pragma unroll
        for (int mt = 0; mt < 4; ++mt)
#pragma unroll
            for (int nt = 0; nt < 4; ++nt)
                o[mt][nt] = __builtin_amdgcn_mfma_f32_16x16x32_bf16(a[mt], b[nt], o[mt][nt], 0, 0, 0);
    }

#pragma unroll
    for (int mt = 0; mt < 4; ++mt) {
#pragma unroll
        for (int e = 0; e < 4; ++e) {
            int i = mt * 16 + lg * 4 + e;
            if (i < 49) {
#pragma unroll
                for (int nt = 0; nt < 4; ++nt) {
                    int col = hh * 64 + nt * 16 + rr;
                    outb[(rowbase + i) * 512 + col] = f2b(o[mt][nt][e] * srow[mt * 4 + e]);
                }
            }
        }
    }
}

// ---------------------------------------------------------------------------
// A[r] = tanh_t[r,:256] . ap_w2 + ap_b2     (one wave per row)
// ---------------------------------------------------------------------------
__global__ __launch_bounds__(256) void ap2_k(const ushort* __restrict__ tb,
                                             const float* __restrict__ w2,
                                             const float* __restrict__ b2,
                                             float* __restrict__ Avec) {
    long row = (long)blockIdx.x * 4 + (threadIdx.x >> 6);
    int l = threadIdx.x & 63;
    ushort4 u = *(const ushort4*)(tb + row * 256 + l * 4);
    float4 wv = *(const float4*)(w2 + l * 4);
    float s = b2f(u.x) * wv.x + b2f(u.y) * wv.y + b2f(u.z) * wv.z + b2f(u.w) * wv.w;
#pragma unroll
    for (int m = 1; m < 64; m <<= 1) s += __shfl_xor(s, m);
    if (l == 0) Avec[row] = s + b2[0];
}

__global__ __launch_bounds__(1024) void smprep_k(const float* __restrict__ A, int M,
                                                 float* __restrict__ sc) {
    __shared__ float red[1024];
    int t = threadIdx.x;
    float m = -3.4e38f;
    for (int i = t; i < M; i += 1024) m = fmaxf(m, A[i]);
    red[t] = m;
    __syncthreads();
    for (int o = 512; o > 0; o >>= 1) {
        if (t < o) red[t] = fmaxf(red[t], red[t + o]);
        __syncthreads();
    }
    float mx = red[0];
    __syncthreads();
    float s = 0.f;
    for (int i = t; i < M; i += 1024) s += __expf(A[i] - mx);
    red[t] = s;
    __syncthreads();
    for (int o = 512; o > 0; o >>= 1) {
        if (t < o) red[t] += red[t + o];
        __syncthreads();
    }
    if (t == 0) {
        sc[0] = mx;
        sc[1] = red[0];
    }
}

__global__ __launch_bounds__(256) void pool1_k(const float* __restrict__ Avec,
                                               const float* __restrict__ sc,
                                               const float* __restrict__ feat,
                                               float* __restrict__ partial) {
    int t = threadIdx.x;
    long base = (long)blockIdx.x * 256;
    float mx = sc[0], rd = 1.f / sc[1];
    float a0 = 0.f, a1 = 0.f;
    for (int i = 0; i < 256; ++i) {
        long tok = base + i;
        float wt = __expf(Avec[tok] - mx) * rd;
        a0 += wt * feat[tok * 512 + t];
        a1 += wt * feat[tok * 512 + t + 256];
    }
    partial[(long)blockIdx.x * 512 + t] = a0;
    partial[(long)blockIdx.x * 512 + t + 256] = a1;
}

__global__ __launch_bounds__(512) void final_k(const float* __restrict__ partial, int NP,
                                               const float* __restrict__ fc2w,
                                               const float* __restrict__ fc2b,
                                               float* __restrict__ out) {
    __shared__ float pooled[512];
    __shared__ float lgs[4];
    int t = threadIdx.x;
    float s = 0.f;
    for (int b = 0; b < NP; ++b) s += partial[(long)b * 512 + t];
    pooled[t] = s;
    __syncthreads();
    if (t < 4) {
        float x = fc2b[t];
        for (int c = 0; c < 512; ++c) x += pooled[c] * fc2w[c * 4 + t];
        lgs[t] = x;
    }
    __syncthreads();
    if (t == 0) {
        float hz[4];
        for (int i = 0; i < 4; ++i) hz[i] = 1.f / (1.f + __expf(-lgs[i]));
        for (int i = 0; i < 4; ++i) out[i] = hz[i];
        float cp = 1.f;
        for (int i = 0; i < 4; ++i) {
            cp *= (1.f - hz[i]);
            out[4 + i] = cp;
        }
        int best = 0;
        for (int i = 1; i < 4; ++i)
            if (lgs[i] > lgs[best]) best = i;
        out[8] = (float)best;
    }
}

// ---------------------------------------------------------------------------
extern "C" void kernel_launch(void* const* d_in, const int* in_sizes, int n_in, void* d_out,
                              int out_size, void* d_ws, size_t ws_size, hipStream_t stream) {
    const float* data = (const float*)d_in[0];
    const float* fc1_w = (const float*)d_in[1];
    const float* fc1_b = (const float*)d_in[2];
    const float* ln1_g = (const float*)d_in[3];
    const float* ln1_b = (const float*)d_in[4];
    const float* wa_qkv_w = (const float*)d_in[5];
    const float* wa_qkv_b = (const float*)d_in[6];
    const float* wa_bt = (const float*)d_in[7];
    const float* wa_proj_w = (const float*)d_in[8];
    const float* wa_proj_b = (const float*)d_in[9];
    const float* n1_g = (const float*)d_in[10];
    const float* n1_b = (const float*)d_in[11];
    const float* sa_qkv_w = (const float*)d_in[12];
    const float* sa_qkv_b = (const float*)d_in[13];
    const float* sa_proj_w = (const float*)d_in[14];
    const float* sa_proj_b = (const float*)d_in[15];
    const float* n2_g = (const float*)d_in[16];
    const float* n2_b = (const float*)d_in[17];
    const float* mlp_w1 = (const float*)d_in[18];
    const float* mlp_b1 = (const float*)d_in[19];
    const float* mlp_w2 = (const float*)d_in[20];
    const float* mlp_b2 = (const float*)d_in[21];
    const float* n3_g = (const float*)d_in[22];
    const float* n3_b = (const float*)d_in[23];
    const float* ap_w1 = (const float*)d_in[24];
    const float* ap_b1 = (const float*)d_in[25];
    const float* ap_w2 = (const float*)d_in[26];
    const float* ap_b2 = (const float*)d_in[27];
    const float* fc2_w = (const float*)d_in[28];
    const float* fc2_b = (const float*)d_in[29];

    const int M = 50176;  // tokens
    const int nM = M / 128;

    char* ws = (char*)d_ws;
    size_t off = 0;
    auto alloc = [&](size_t bytes) {
        size_t p = off;
        off = (off + bytes + 255) & ~(size_t)255;
        return (void*)(ws + p);
    };

    ushort* fc1T = (ushort*)alloc((size_t)512 * 1024 * 2);
    ushort* waqkvT = (ushort*)alloc((size_t)1536 * 512 * 2);
    ushort* waprojT = (ushort*)alloc((size_t)512 * 512 * 2);
    ushort* saqkvT = (ushort*)alloc((size_t)1536 * 512 * 2);
    ushort* saprojT = (ushort*)alloc((size_t)512 * 512 * 2);
    ushort* mlp1T = (ushort*)alloc((size_t)512 * 512 * 2);
    ushort* mlp2T = (ushort*)alloc((size_t)512 * 512 * 2);
    ushort* ap1T = (ushort*)alloc((size_t)256 * 512 * 2);
    int* pwtab = (int*)alloc(512 * 4);
    float* sc = (float*)alloc(64);
    float* Avec = (float*)alloc((size_t)M * 4);
    float* partial = (float*)alloc((size_t)196 * 512 * 4);
    float* hb = (float*)alloc((size_t)M * 512 * 4);
    float* fb = (float*)alloc((size_t)M * 512 * 4);
    ushort* lnb = (ushort*)alloc((size_t)M * 512 * 2);
    ushort* attnout = (ushort*)alloc((size_t)M * 512 * 2);
    ushort* qkvb = (ushort*)alloc((size_t)M * 1536 * 2);
    ushort* dataB = qkvb;            // [M][1024] bf16, dead once WA qkv runs
    ushort* tb = qkvb;               // tanh output (M x 256), after SA attn done
    ushort* wavT = (ushort*)fb;      // V^T for WA: fb unused until WA proj (64 MB < 103 MB)
    ushort* savT = (ushort*)hb;      // V^T for SA: h dead after WA proj

    // weight transposes + casts + tables
    castT_k<<<(512 * 1024 + 255) / 256, 256, 0, stream>>>(fc1_w, fc1T, 1024, 512);
    castT_k<<<(512 * 1536 + 255) / 256, 256, 0, stream>>>(wa_qkv_w, waqkvT, 512, 1536);
    castT_k<<<(512 * 512 + 255) / 256, 256, 0, stream>>>(wa_proj_w, waprojT, 512, 512);
    castT_k<<<(512 * 1536 + 255) / 256, 256, 0, stream>>>(sa_qkv_w, saqkvT, 512, 1536);
    castT_k<<<(512 * 512 + 255) / 256, 256, 0, stream>>>(sa_proj_w, saprojT, 512, 512);
    castT_k<<<(512 * 512 + 255) / 256, 256, 0, stream>>>(mlp_w1, mlp1T, 512, 512);
    castT_k<<<(512 * 512 + 255) / 256, 256, 0, stream>>>(mlp_w2, mlp2T, 512, 512);
    castT_k<<<(256 * 512 + 255) / 256, 256, 0, stream>>>(ap_w1, ap1T, 512, 256);
    pw_k<<<1, 512, 0, stream>>>(pwtab);
    dcast_k<<<25088, 256, 0, stream>>>(data, dataB);

    // fc1 + relu -> h
    gemm_k<0, false, false><<<nM * 4, 256, 0, stream>>>(dataB, 1024, fc1T, fc1_b, nullptr, hb,
                                                        nullptr, 512, 1024);
    // ln1(h) -> lnb
    ln_k<<<M / 4, 256, 0, stream>>>(hb, ln1_g, ln1_b, lnb, nullptr);
    // WA qkv
    gemm_k<1, false, false><<<nM * 12, 256, 0, stream>>>(lnb, 512, waqkvT, wa_qkv_b, nullptr,
                                                         nullptr, qkvb, 1536, 512);
    // WA V transpose (zero-padded)
    vtt_k<<<8192, 64, 0, stream>>>(qkvb, wavT);
    // WA attention (with bias)
    attn_k<true><<<8192, 64, 0, stream>>>(qkvb, wavT, data, pwtab, wa_bt, attnout);
    // WA proj: f = gelu(h + out)
    gemm_k<2, false, false><<<nM * 4, 256, 0, stream>>>(attnout, 512, waprojT, wa_proj_b, hb, fb,
                                                        nullptr, 512, 512);
    // norm1(f) -> lnb
    ln_k<<<M / 4, 256, 0, stream>>>(fb, n1_g, n1_b, lnb, nullptr);
    // SA qkv (permuted gather of A rows)
    gemm_k<1, true, false><<<nM * 12, 256, 0, stream>>>(lnb, 512, saqkvT, sa_qkv_b, nullptr,
                                                        nullptr, qkvb, 1536, 512);
    // SA V transpose (zero-padded)
    vtt_k<<<8192, 64, 0, stream>>>(qkvb, savT);
    // SA attention (no bias)
    attn_k<false><<<8192, 64, 0, stream>>>(qkvb, savT, nullptr, nullptr, nullptr, attnout);
    // SA proj: f[perm] += out
    gemm_k<3, false, true><<<nM * 4, 256, 0, stream>>>(attnout, 512, saprojT, sa_proj_b, nullptr,
                                                       fb, nullptr, 512, 512);
    // norm2(f) -> lnb
    ln_k<<<M / 4, 256, 0, stream>>>(fb, n2_g, n2_b, lnb, nullptr);
    // mlp1: hidden = gelu(lnb @ w1 + b1) -> attnout
    gemm_k<4, false, false><<<nM * 4, 256, 0, stream>>>(lnb, 512, mlp1T, mlp_b1, nullptr, nullptr,
                                                        attnout, 512, 512);
    // mlp2: f += hidden @ w2 + b2
    gemm_k<3, false, false><<<nM * 4, 256, 0, stream>>>(attnout, 512, mlp2T, mlp_b2, nullptr, fb,
                                                        nullptr, 512, 512);
    // norm3(f) -> feat (f32 into hb) + lnb
    ln_k<<<M / 4, 256, 0, stream>>>(fb, n3_g, n3_b, lnb, hb);
    // ap1: t = tanh(lnb @ ap_w1 + b1) -> tb
    gemm_k<5, false, false><<<nM * 2, 256, 0, stream>>>(lnb, 512, ap1T, ap_b1, nullptr, nullptr,
                                                        tb, 256, 512);
    // A = t @ ap_w2 + b2
    ap2_k<<<M / 4, 256, 0, stream>>>(tb, ap_w2, ap_b2, Avec);
    // softmax prep
    smprep_k<<<1, 1024, 0, stream>>>(Avec, M, sc);
    // pooled partials
    pool1_k<<<196, 256, 0, stream>>>(Avec, sc, hb, partial);
    // final head
    final_k<<<1, 512, 0, stream>>>(partial, 196, fc2_w, fc2_b, (float*)d_out);
}

// Round 7
// 1206.679 us; speedup vs baseline: 1.1423x; 1.0296x over previous
//
#include <hip/hip_runtime.h>
#include <hip/hip_bf16.h>
#include <math.h>

typedef short bf16x8 __attribute__((ext_vector_type(8)));
typedef float f32x4 __attribute__((ext_vector_type(4)));

#define DEV __device__ __forceinline__

DEV ushort f2b(float x) {
    unsigned u = __float_as_uint(x);
    u += 0x7fffu + ((u >> 16) & 1u);
    return (ushort)(u >> 16);
}
DEV float b2f(ushort h) { return __uint_as_float(((unsigned)h) << 16); }
DEV float gelu_f(float x) { return 0.5f * x * (1.0f + erff(x * 0.70710678118654752f)); }

// async global->LDS, 16B per lane; LDS dest wave-uniform base (lane*16 added by HW)
DEV void gl2lds16(const void* g, void* l) {
    __builtin_amdgcn_global_load_lds(
        (const __attribute__((address_space(1))) void*)(uintptr_t)g,
        (__attribute__((address_space(3))) void*)(uintptr_t)l, 16, 0, 0);
}

#define BAR() __builtin_amdgcn_s_barrier()

// ---------------------------------------------------------------------------
// Weight transpose + cast:  Wt[n*K + k] = bf16(W[k*N + n])
// ---------------------------------------------------------------------------
__global__ __launch_bounds__(256) void castT_k(const float* __restrict__ W,
                                               ushort* __restrict__ Wt, int K, int N) {
    long i = (long)blockIdx.x * 256 + threadIdx.x;
    if (i < (long)K * N) {
        int k = (int)(i / N), n = (int)(i % N);
        Wt[(long)n * K + k] = f2b(W[i]);
    }
}

// data[:, 2:1026] f32 -> bf16 [50176][1024]
__global__ __launch_bounds__(256) void dcast_k(const float* __restrict__ data,
                                               ushort* __restrict__ out) {
    long i = ((long)blockIdx.x * 256 + threadIdx.x) * 8;
    int r = (int)(i >> 10);
    int c = (int)(i & 1023);
    const float* p = data + (long)r * 1026 + 2 + c;
    float2 f0 = *(const float2*)p;
    float2 f1 = *(const float2*)(p + 2);
    float2 f2 = *(const float2*)(p + 4);
    float2 f3 = *(const float2*)(p + 6);
    int4 pk;
    pk.x = (int)f2b(f0.x) | ((int)f2b(f0.y) << 16);
    pk.y = (int)f2b(f1.x) | ((int)f2b(f1.y) << 16);
    pk.z = (int)f2b(f2.x) | ((int)f2b(f2.y) << 16);
    pk.w = (int)f2b(f3.x) | ((int)f2b(f3.y) << 16);
    *(int4*)(&out[i]) = pk;
}

// ---------------------------------------------------------------------------
// piecewise_index |.| table for d = 0..511
// ---------------------------------------------------------------------------
__global__ void pw_k(int* __restrict__ pw) {
    int d = threadIdx.x;
    int v;
    if (d == 0) v = 0;
    else if (d <= 3) v = 1;
    else {
        float t = logf((float)d / 1.9f) / 1.7917594692280552f * 3.8f;
        int r = (int)rintf(t);
        v = r < 7 ? r : 7;
    }
    pw[d] = v;
}

// ---------------------------------------------------------------------------
// GEMM: C[M x N] = A[M x K] @ B[K x N] (+bias, epilogues).  A bf16 [M][lda],
// B as Bt[N][K] bf16.  BM=BN=128, BK=32, 4 waves (2x2 of 64x64), 16x16x32 MFMA.
// 3-buffer LDS pipeline (48 KB), prefetch distance 2: stage(t+2) issued each
// iter into buffer sb=(t+2)%3 (EXPLICIT rotating counter — round-6 bug was a
// wrong inline expression clobbering live buffers). Steady-state
// s_waitcnt vmcnt(8): 12 loads in flight after stage, drain only tile-t's 4.
// WAR safe: buffer (t+2)%3 was last read at iter t-1 whose BAR2 rendezvous
// precedes this iter's stage issue in program order for all waves.
// Staging: linear LDS dest, pre-swizzled source granule tg=(tid&3)^((tid>>3)&3);
// read slot = lg ^ ((row>>1)&3)  -> 2-way max bank aliasing (free).
// Block swizzle: bijective XCD chunking.  3 blocks/CU (LDS 48K, launch_bounds).
// EPI: 0 relu->f32  1 +bias->bf16  2 gelu(hres+x)->f32  3 outF[perm?]+=x
//      4 gelu->bf16  5 tanh->bf16
// ---------------------------------------------------------------------------
template <int EPI, bool PERMA, bool PERMOUT>
__global__ __launch_bounds__(256, 3) void gemm_k(const ushort* __restrict__ A, long lda,
                                                 const ushort* __restrict__ Bt,
                                                 const float* __restrict__ bias,
                                                 const float* __restrict__ hres,
                                                 float* __restrict__ outF,
                                                 ushort* __restrict__ outB, int N, int K) {
    __shared__ ushort sh[3][2][128 * 32];  // 48 KB
    const int tid = threadIdx.x;
    const int nN = N >> 7;
    // bijective XCD-chunk swizzle (m204)
    int nwg = gridDim.x;
    int xcd = blockIdx.x & 7, lin = blockIdx.x >> 3;
    int q = nwg >> 3, r8 = nwg & 7;
    int swz = (xcd < r8 ? xcd * (q + 1) : r8 * (q + 1) + (xcd - r8) * q) + lin;
    const long m0 = (long)(swz / nN) * 128;
    const int n0 = (swz % nN) * 128;
    const int l = tid & 63, wv = tid >> 6;
    const int wm = (wv >> 1) * 64, wn = (wv & 1) * 64;
    const int rr = l & 15, lg = l >> 4;
    const int trow = tid >> 2;                    // row within 64-row chunk
    const int tg = (tid & 3) ^ ((tid >> 3) & 3);  // pre-swizzled source granule

    f32x4 acc[4][4];
#pragma unroll
    for (int a = 0; a < 4; ++a)
#pragma unroll
        for (int b = 0; b < 4; ++b) acc[a][b] = (f32x4){0.f, 0.f, 0.f, 0.f};

    auto stage = [&](int buf, int k0) {
#pragma unroll
        for (int c = 0; c < 2; ++c) {
            int row = c * 64 + trow;
            long arow = m0 + row;
            if (PERMA) {
                int qq = (int)arow / 49;
                int ss = (int)arow - qq * 49;
                arow = (long)ss * 1024 + qq;
            }
            gl2lds16(A + arow * lda + k0 + tg * 8, &sh[buf][0][c * 2048 + wv * 512]);
        }
#pragma unroll
        for (int c = 0; c < 2; ++c) {
            int row = c * 64 + trow;
            gl2lds16(Bt + (long)(n0 + row) * K + k0 + tg * 8, &sh[buf][1][c * 2048 + wv * 512]);
        }
    };

    const int nT = K >> 5;  // >= 8 for all our K
    stage(0, 0);
    stage(1, 32);
    int cur = 0;  // buffer holding tile t
    int sb = 2;   // buffer for tile t+2

    for (int t = 0; t < nT; ++t) {
        int ahead = nT - 1 - t;  // future tiles with loads in flight after this stage
        if (t + 2 < nT) stage(sb, (t + 2) * 32);
        // drain only tile-t's 4 loads
        if (ahead >= 2)
            asm volatile("s_waitcnt vmcnt(8)" ::: "memory");
        else if (ahead == 1)
            asm volatile("s_waitcnt vmcnt(4)" ::: "memory");
        else
            asm volatile("s_waitcnt vmcnt(0)" ::: "memory");
        BAR();  // all waves: buffer cur fully landed
        bf16x8 a[4], b[4];
#pragma unroll
        for (int mt = 0; mt < 4; ++mt) {
            int row = wm + mt * 16 + rr;
            int slot = lg ^ ((row >> 1) & 3);
            a[mt] = *(const bf16x8*)(&sh[cur][0][row * 32 + slot * 8]);
        }
#pragma unroll
        for (int nt = 0; nt < 4; ++nt) {
            int row = wn + nt * 16 + rr;
            int slot = lg ^ ((row >> 1) & 3);
            b[nt] = *(const bf16x8*)(&sh[cur][1][row * 32 + slot * 8]);
        }
#pragma unroll
        for (int mt = 0; mt < 4; ++mt)
#pragma unroll
            for (int nt = 0; nt < 4; ++nt)
                acc[mt][nt] =
                    __builtin_amdgcn_mfma_f32_16x16x32_bf16(a[mt], b[nt], acc[mt][nt], 0, 0, 0);
        BAR();  // reads of buf cur done in all waves before iter t+1 restages it
        cur = (cur == 2) ? 0 : cur + 1;
        sb = (sb == 2) ? 0 : sb + 1;
    }

#pragma unroll
    for (int mt = 0; mt < 4; ++mt) {
#pragma unroll
        for (int e = 0; e < 4; ++e) {
            long gr = m0 + wm + mt * 16 + lg * 4 + e;
            long orow = gr;
            if (PERMOUT) {
                int qq = (int)gr / 49;
                int ss = (int)gr - qq * 49;
                orow = (long)ss * 1024 + qq;
            }
#pragma unroll
            for (int nt = 0; nt < 4; ++nt) {
                int gc = n0 + wn + nt * 16 + rr;
                float v = acc[mt][nt][e] + bias[gc];
                if (EPI == 0) {
                    outF[gr * N + gc] = fmaxf(v, 0.f);
                } else if (EPI == 1) {
                    outB[gr * N + gc] = f2b(v);
                } else if (EPI == 2) {
                    outF[gr * N + gc] = gelu_f(hres[gr * N + gc] + v);
                } else if (EPI == 3) {
                    outF[orow * N + gc] += v;
                } else if (EPI == 4) {
                    outB[gr * N + gc] = f2b(gelu_f(v));
                } else {
                    outB[gr * N + gc] = f2b(tanhf(v));
                }
            }
        }
    }
}

// ---------------------------------------------------------------------------
// V transpose: vtp[(w*8+h)*4096 + d*64 + t] = V[w,t,h,d], zero-padded t>=49.
// ---------------------------------------------------------------------------
__global__ __launch_bounds__(64) void vtt_k(const ushort* __restrict__ qkv,
                                            ushort* __restrict__ vtp) {
    __shared__ ushort lds[49 * 64];
    const int l = threadIdx.x;
    const int w = blockIdx.x >> 3, hh = blockIdx.x & 7;
    const long rowbase = (long)w * 49;
    for (int idx = l; idx < 49 * 8; idx += 64) {
        int r = idx >> 3, g = idx & 7;
        int4 v = *(const int4*)(qkv + (rowbase + r) * 1536 + 1024 + hh * 64 + g * 8);
        *(int4*)(&lds[r * 64 + ((g ^ (r & 7)) * 8)]) = v;
    }
    __syncthreads();
    ushort* outb = vtp + ((long)w * 8 + hh) * 4096;
#pragma unroll 8
    for (int d = 0; d < 64; ++d) {
        ushort v = 0;
        if (l < 49) v = lds[l * 64 + (((d >> 3) ^ (l & 7)) * 8) + (d & 7)];
        outb[d * 64 + l] = v;
    }
}

// ---------------------------------------------------------------------------
// LayerNorm over rows of 512. 256 thr = 4 waves, one row per wave.
// ---------------------------------------------------------------------------
__global__ __launch_bounds__(256) void ln_k(const float* __restrict__ x,
                                            const float* __restrict__ g,
                                            const float* __restrict__ b,
                                            ushort* __restrict__ outB, float* __restrict__ outF) {
    long row = (long)blockIdx.x * 4 + (threadIdx.x >> 6);
    int l = threadIdx.x & 63;
    const float* xr = x + row * 512 + l * 8;
    float4 v0 = *(const float4*)xr;
    float4 v1 = *(const float4*)(xr + 4);
    float s = v0.x + v0.y + v0.z + v0.w + v1.x + v1.y + v1.z + v1.w;
    float q = v0.x * v0.x + v0.y * v0.y + v0.z * v0.z + v0.w * v0.w + v1.x * v1.x + v1.y * v1.y +
              v1.z * v1.z + v1.w * v1.w;
#pragma unroll
    for (int m = 1; m < 64; m <<= 1) {
        s += __shfl_xor(s, m);
        q += __shfl_xor(q, m);
    }
    float mean = s * (1.f / 512.f);
    float var = q * (1.f / 512.f) - mean * mean;
    float rstd = rsqrtf(var + 1e-5f);
    float4 g0 = *(const float4*)(g + l * 8);
    float4 g1 = *(const float4*)(g + l * 8 + 4);
    float4 b0 = *(const float4*)(b + l * 8);
    float4 b1 = *(const float4*)(b + l * 8 + 4);
    float y[8];
    y[0] = (v0.x - mean) * rstd * g0.x + b0.x;
    y[1] = (v0.y - mean) * rstd * g0.y + b0.y;
    y[2] = (v0.z - mean) * rstd * g0.z + b0.z;
    y[3] = (v0.w - mean) * rstd * g0.w + b0.w;
    y[4] = (v1.x - mean) * rstd * g1.x + b1.x;
    y[5] = (v1.y - mean) * rstd * g1.y + b1.y;
    y[6] = (v1.z - mean) * rstd * g1.z + b1.z;
    y[7] = (v1.w - mean) * rstd * g1.w + b1.w;
    if (outB) {
        int4 pk;
        pk.x = (int)f2b(y[0]) | ((int)f2b(y[1]) << 16);
        pk.y = (int)f2b(y[2]) | ((int)f2b(y[3]) << 16);
        pk.z = (int)f2b(y[4]) | ((int)f2b(y[5]) << 16);
        pk.w = (int)f2b(y[6]) | ((int)f2b(y[7]) << 16);
        *(int4*)(&outB[row * 512 + l * 8]) = pk;
    }
    if (outF) {
        float4 o0 = {y[0], y[1], y[2], y[3]};
        float4 o1 = {y[4], y[5], y[6], y[7]};
        *(float4*)(&outF[row * 512 + l * 8]) = o0;
        *(float4*)(&outF[row * 512 + l * 8 + 4]) = o1;
    }
}

// ---------------------------------------------------------------------------
// Fused per-(window,head) attention. 1 wave/block, 49 tokens padded to 64.
// Q,K fragments direct from qkv; V^T fragments direct from vtp (zero-padded
// by vtt_k). Only P goes through LDS. s_setprio(1) wraps MFMA clusters (T5).
// ---------------------------------------------------------------------------
template <bool BIAS>
__global__ __launch_bounds__(64) void attn_k(const ushort* __restrict__ qkv,
                                             const ushort* __restrict__ vtp,
                                             const float* __restrict__ cdata,
                                             const int* __restrict__ pwt,
                                             const float* __restrict__ btg,
                                             ushort* __restrict__ outb) {
    __shared__ ushort ps[4096];
    __shared__ float cx[64], cy[64], bt[16];
    __shared__ unsigned char pwu[512];

    const int l = threadIdx.x;
    const int w = blockIdx.x >> 3, hh = blockIdx.x & 7;
    const long rowbase = (long)w * 49;
    const ushort* vbase = vtp + ((long)w * 8 + hh) * 4096;
    const int rr = l & 15, lg = l >> 4;

    if (BIAS) {
        if (l < 49) {
            cx[l] = cdata[(rowbase + l) * 1026];
            cy[l] = cdata[(rowbase + l) * 1026 + 1];
        }
        if (l < 15) bt[l] = btg[l * 8 + hh];
        for (int i = l; i < 512; i += 64) pwu[i] = (unsigned char)pwt[i];
    }

    // QK^T: direct global fragment loads
    f32x4 s[4][4];
#pragma unroll
    for (int a = 0; a < 4; ++a)
#pragma unroll
        for (int b = 0; b < 4; ++b) s[a][b] = (f32x4){0.f, 0.f, 0.f, 0.f};

    const bf16x8 zfrag = {0, 0, 0, 0, 0, 0, 0, 0};
#pragma unroll
    for (int kk = 0; kk < 2; ++kk) {
        bf16x8 a[4], b[4];
#pragma unroll
        for (int mt = 0; mt < 4; ++mt) {
            int i = mt * 16 + rr;
            a[mt] = (i < 49) ? *(const bf16x8*)(qkv + (rowbase + i) * 1536 + hh * 64 +
                                                (kk * 4 + lg) * 8)
                             : zfrag;
        }
#pragma unroll
        for (int nt = 0; nt < 4; ++nt) {
            int j = nt * 16 + rr;
            b[nt] = (j < 49) ? *(const bf16x8*)(qkv + (rowbase + j) * 1536 + 512 + hh * 64 +
                                                (kk * 4 + lg) * 8)
                             : zfrag;
        }
        __builtin_amdgcn_s_setprio(1);
#pragma unroll
        for (int mt = 0; mt < 4; ++mt)
#pragma unroll
            for (int nt = 0; nt < 4; ++nt)
                s[mt][nt] = __builtin_amdgcn_mfma_f32_16x16x32_bf16(a[mt], b[nt], s[mt][nt], 0, 0, 0);
        __builtin_amdgcn_s_setprio(0);
    }
    __syncthreads();

    // scale + bias + padding mask, in place; per-row local max
    float mrow[16], srow[16];
#pragma unroll
    for (int mt = 0; mt < 4; ++mt) {
#pragma unroll
        for (int e = 0; e < 4; ++e) {
            int i = mt * 16 + lg * 4 + e;
            float mloc = -1e30f;
#pragma unroll
            for (int nt = 0; nt < 4; ++nt) {
                int j = nt * 16 + rr;
                float v = s[mt][nt][e] * 0.125f;
                if (j >= 49) {
                    v = -1e30f;
                } else if (BIAS) {
                    if (i < 49) {
                        int dx = (int)fabsf(cx[i] - cx[j]);
                        int dy = (int)fabsf(cy[i] - cy[j]);
                        v += bt[pwu[dx] + pwu[dy]];
                    }
                }
                s[mt][nt][e] = v;
                mloc = fmaxf(mloc, v);
            }
            mrow[mt * 4 + e] = mloc;
        }
    }
    // batched max reduce across the 16 rr lanes (16 independent rows per round)
#pragma unroll
    for (int msk = 1; msk < 16; msk <<= 1)
#pragma unroll
        for (int r = 0; r < 16; ++r) mrow[r] = fmaxf(mrow[r], __shfl_xor(mrow[r], msk));
    // exp + local sum + P write
#pragma unroll
    for (int mt = 0; mt < 4; ++mt) {
#pragma unroll
        for (int e = 0; e < 4; ++e) {
            int r = mt * 4 + e;
            int i = mt * 16 + lg * 4 + e;
            float sm = 0.f;
#pragma unroll
            for (int nt = 0; nt < 4; ++nt) {
                int j = nt * 16 + rr;
                float p = __expf(s[mt][nt][e] - mrow[r]);
                sm += p;
                ps[i * 64 + (((j >> 3) ^ (i & 7)) * 8) + (j & 7)] = f2b(p);
            }
            srow[r] = sm;
        }
    }
#pragma unroll
    for (int msk = 1; msk < 16; msk <<= 1)
#pragma unroll
        for (int r = 0; r < 16; ++r) srow[r] += __shfl_xor(srow[r], msk);
#pragma unroll
    for (int r = 0; r < 16; ++r) srow[r] = 1.f / srow[r];
    __syncthreads();

    f32x4 o[4][4];
#pragma unroll
    for (int a = 0; a < 4; ++a)
#pragma unroll
        for (int b = 0; b < 4; ++b) o[a][b] = (f32x4){0.f, 0.f, 0.f, 0.f};

#pragma unroll
    for (int kk = 0; kk < 2; ++kk) {
        bf16x8 a[4], b[4];
#pragma unroll
        for (int mt = 0; mt < 4; ++mt) {
            int i = mt * 16 + rr;
            int slot = (kk * 4 + lg) ^ (i & 7);
            a[mt] = *(const bf16x8*)(&ps[i * 64 + slot * 8]);
        }
#pragma unroll
        for (int nt = 0; nt < 4; ++nt) {
            int d = nt * 16 + rr;
            b[nt] = *(const bf16x8*)(vbase + d * 64 + (kk * 4 + lg) * 8);
        }
        __builtin_amdgcn_s_setprio(1);
#pragma unroll
        for (int mt = 0; mt < 4; ++mt)
#pragma unroll
            for (int nt = 0; nt < 4; ++nt)
                o[mt][nt] = __builtin_amdgcn_mfma_f32_16x16x32_bf16(a[mt], b[nt], o[mt][nt], 0, 0, 0);
        __builtin_amdgcn_s_setprio(0);
    }

#pragma unroll
    for (int mt = 0; mt < 4; ++mt) {
#pragma unroll
        for (int e = 0; e < 4; ++e) {
            int i = mt * 16 + lg * 4 + e;
            if (i < 49) {
#pragma unroll
                for (int nt = 0; nt < 4; ++nt) {
                    int col = hh * 64 + nt * 16 + rr;
                    outb[(rowbase + i) * 512 + col] = f2b(o[mt][nt][e] * srow[mt * 4 + e]);
                }
            }
        }
    }
}

// ---------------------------------------------------------------------------
// A[r] = tanh_t[r,:256] . ap_w2 + ap_b2     (one wave per row)
// ---------------------------------------------------------------------------
__global__ __launch_bounds__(256) void ap2_k(const ushort* __restrict__ tb,
                                             const float* __restrict__ w2,
                                             const float* __restrict__ b2,
                                             float* __restrict__ Avec) {
    long row = (long)blockIdx.x * 4 + (threadIdx.x >> 6);
    int l = threadIdx.x & 63;
    ushort4 u = *(const ushort4*)(tb + row * 256 + l * 4);
    float4 wv = *(const float4*)(w2 + l * 4);
    float s = b2f(u.x) * wv.x + b2f(u.y) * wv.y + b2f(u.z) * wv.z + b2f(u.w) * wv.w;
#pragma unroll
    for (int m = 1; m < 64; m <<= 1) s += __shfl_xor(s, m);
    if (l == 0) Avec[row] = s + b2[0];
}

__global__ __launch_bounds__(1024) void smprep_k(const float* __restrict__ A, int M,
                                                 float* __restrict__ sc) {
    __shared__ float red[1024];
    int t = threadIdx.x;
    float m = -3.4e38f;
    for (int i = t; i < M; i += 1024) m = fmaxf(m, A[i]);
    red[t] = m;
    __syncthreads();
    for (int o = 512; o > 0; o >>= 1) {
        if (t < o) red[t] = fmaxf(red[t], red[t + o]);
        __syncthreads();
    }
    float mx = red[0];
    __syncthreads();
    float s = 0.f;
    for (int i = t; i < M; i += 1024) s += __expf(A[i] - mx);
    red[t] = s;
    __syncthreads();
    for (int o = 512; o > 0; o >>= 1) {
        if (t < o) red[t] += red[t + o];
        __syncthreads();
    }
    if (t == 0) {
        sc[0] = mx;
        sc[1] = red[0];
    }
}

__global__ __launch_bounds__(256) void pool1_k(const float* __restrict__ Avec,
                                               const float* __restrict__ sc,
                                               const float* __restrict__ feat,
                                               float* __restrict__ partial) {
    int t = threadIdx.x;
    long base = (long)blockIdx.x * 256;
    float mx = sc[0], rd = 1.f / sc[1];
    float a0 = 0.f, a1 = 0.f;
    for (int i = 0; i < 256; ++i) {
        long tok = base + i;
        float wt = __expf(Avec[tok] - mx) * rd;
        a0 += wt * feat[tok * 512 + t];
        a1 += wt * feat[tok * 512 + t + 256];
    }
    partial[(long)blockIdx.x * 512 + t] = a0;
    partial[(long)blockIdx.x * 512 + t + 256] = a1;
}

__global__ __launch_bounds__(512) void final_k(const float* __restrict__ partial, int NP,
                                               const float* __restrict__ fc2w,
                                               const float* __restrict__ fc2b,
                                               float* __restrict__ out) {
    __shared__ float pooled[512];
    __shared__ float lgs[4];
    int t = threadIdx.x;
    float s = 0.f;
    for (int b = 0; b < NP; ++b) s += partial[(long)b * 512 + t];
    pooled[t] = s;
    __syncthreads();
    if (t < 4) {
        float x = fc2b[t];
        for (int c = 0; c < 512; ++c) x += pooled[c] * fc2w[c * 4 + t];
        lgs[t] = x;
    }
    __syncthreads();
    if (t == 0) {
        float hz[4];
        for (int i = 0; i < 4; ++i) hz[i] = 1.f / (1.f + __expf(-lgs[i]));
        for (int i = 0; i < 4; ++i) out[i] = hz[i];
        float cp = 1.f;
        for (int i = 0; i < 4; ++i) {
            cp *= (1.f - hz[i]);
            out[4 + i] = cp;
        }
        int best = 0;
        for (int i = 1; i < 4; ++i)
            if (lgs[i] > lgs[best]) best = i;
        out[8] = (float)best;
    }
}

// ---------------------------------------------------------------------------
extern "C" void kernel_launch(void* const* d_in, const int* in_sizes, int n_in, void* d_out,
                              int out_size, void* d_ws, size_t ws_size, hipStream_t stream) {
    const float* data = (const float*)d_in[0];
    const float* fc1_w = (const float*)d_in[1];
    const float* fc1_b = (const float*)d_in[2];
    const float* ln1_g = (const float*)d_in[3];
    const float* ln1_b = (const float*)d_in[4];
    const float* wa_qkv_w = (const float*)d_in[5];
    const float* wa_qkv_b = (const float*)d_in[6];
    const float* wa_bt = (const float*)d_in[7];
    const float* wa_proj_w = (const float*)d_in[8];
    const float* wa_proj_b = (const float*)d_in[9];
    const float* n1_g = (const float*)d_in[10];
    const float* n1_b = (const float*)d_in[11];
    const float* sa_qkv_w = (const float*)d_in[12];
    const float* sa_qkv_b = (const float*)d_in[13];
    const float* sa_proj_w = (const float*)d_in[14];
    const float* sa_proj_b = (const float*)d_in[15];
    const float* n2_g = (const float*)d_in[16];
    const float* n2_b = (const float*)d_in[17];
    const float* mlp_w1 = (const float*)d_in[18];
    const float* mlp_b1 = (const float*)d_in[19];
    const float* mlp_w2 = (const float*)d_in[20];
    const float* mlp_b2 = (const float*)d_in[21];
    const float* n3_g = (const float*)d_in[22];
    const float* n3_b = (const float*)d_in[23];
    const float* ap_w1 = (const float*)d_in[24];
    const float* ap_b1 = (const float*)d_in[25];
    const float* ap_w2 = (const float*)d_in[26];
    const float* ap_b2 = (const float*)d_in[27];
    const float* fc2_w = (const float*)d_in[28];
    const float* fc2_b = (const float*)d_in[29];

    const int M = 50176;  // tokens
    const int nM = M / 128;

    char* ws = (char*)d_ws;
    size_t off = 0;
    auto alloc = [&](size_t bytes) {
        size_t p = off;
        off = (off + bytes + 255) & ~(size_t)255;
        return (void*)(ws + p);
    };

    ushort* fc1T = (ushort*)alloc((size_t)512 * 1024 * 2);
    ushort* waqkvT = (ushort*)alloc((size_t)1536 * 512 * 2);
    ushort* waprojT = (ushort*)alloc((size_t)512 * 512 * 2);
    ushort* saqkvT = (ushort*)alloc((size_t)1536 * 512 * 2);
    ushort* saprojT = (ushort*)alloc((size_t)512 * 512 * 2);
    ushort* mlp1T = (ushort*)alloc((size_t)512 * 512 * 2);
    ushort* mlp2T = (ushort*)alloc((size_t)512 * 512 * 2);
    ushort* ap1T = (ushort*)alloc((size_t)256 * 512 * 2);
    int* pwtab = (int*)alloc(512 * 4);
    float* sc = (float*)alloc(64);
    float* Avec = (float*)alloc((size_t)M * 4);
    float* partial = (float*)alloc((size_t)196 * 512 * 4);
    float* hb = (float*)alloc((size_t)M * 512 * 4);
    float* fb = (float*)alloc((size_t)M * 512 * 4);
    ushort* lnb = (ushort*)alloc((size_t)M * 512 * 2);
    ushort* attnout = (ushort*)alloc((size_t)M * 512 * 2);
    ushort* qkvb = (ushort*)alloc((size_t)M * 1536 * 2);
    ushort* dataB = qkvb;        // [M][1024] bf16, dead once WA qkv runs
    ushort* tb = qkvb;           // tanh output (M x 256), after SA attn done
    ushort* wavT = (ushort*)fb;  // V^T for WA: fb unused until WA proj
    ushort* savT = (ushort*)hb;  // V^T for SA: h dead after WA proj

    // weight transposes + casts + tables
    castT_k<<<(512 * 1024 + 255) / 256, 256, 0, stream>>>(fc1_w, fc1T, 1024, 512);
    castT_k<<<(512 * 1536 + 255) / 256, 256, 0, stream>>>(wa_qkv_w, waqkvT, 512, 1536);
    castT_k<<<(512 * 512 + 255) / 256, 256, 0, stream>>>(wa_proj_w, waprojT, 512, 512);
    castT_k<<<(512 * 1536 + 255) / 256, 256, 0, stream>>>(sa_qkv_w, saqkvT, 512, 1536);
    castT_k<<<(512 * 512 + 255) / 256, 256, 0, stream>>>(sa_proj_w, saprojT, 512, 512);
    castT_k<<<(512 * 512 + 255) / 256, 256, 0, stream>>>(mlp_w1, mlp1T, 512, 512);
    castT_k<<<(512 * 512 + 255) / 256, 256, 0, stream>>>(mlp_w2, mlp2T, 512, 512);
    castT_k<<<(256 * 512 + 255) / 256, 256, 0, stream>>>(ap_w1, ap1T, 512, 256);
    pw_k<<<1, 512, 0, stream>>>(pwtab);
    dcast_k<<<25088, 256, 0, stream>>>(data, dataB);

    // fc1 + relu -> h
    gemm_k<0, false, false><<<nM * 4, 256, 0, stream>>>(dataB, 1024, fc1T, fc1_b, nullptr, hb,
                                                        nullptr, 512, 1024);
    // ln1(h) -> lnb
    ln_k<<<M / 4, 256, 0, stream>>>(hb, ln1_g, ln1_b, lnb, nullptr);
    // WA qkv
    gemm_k<1, false, false><<<nM * 12, 256, 0, stream>>>(lnb, 512, waqkvT, wa_qkv_b, nullptr,
                                                         nullptr, qkvb, 1536, 512);
    // WA V transpose (zero-padded)
    vtt_k<<<8192, 64, 0, stream>>>(qkvb, wavT);
    // WA attention (with bias)
    attn_k<true><<<8192, 64, 0, stream>>>(qkvb, wavT, data, pwtab, wa_bt, attnout);
    // WA proj: f = gelu(h + out)
    gemm_k<2, false, false><<<nM * 4, 256, 0, stream>>>(attnout, 512, waprojT, wa_proj_b, hb, fb,
                                                        nullptr, 512, 512);
    // norm1(f) -> lnb
    ln_k<<<M / 4, 256, 0, stream>>>(fb, n1_g, n1_b, lnb, nullptr);
    // SA qkv (permuted gather of A rows)
    gemm_k<1, true, false><<<nM * 12, 256, 0, stream>>>(lnb, 512, saqkvT, sa_qkv_b, nullptr,
                                                        nullptr, qkvb, 1536, 512);
    // SA V transpose (zero-padded)
    vtt_k<<<8192, 64, 0, stream>>>(qkvb, savT);
    // SA attention (no bias)
    attn_k<false><<<8192, 64, 0, stream>>>(qkvb, savT, nullptr, nullptr, nullptr, attnout);
    // SA proj: f[perm] += out
    gemm_k<3, false, true><<<nM * 4, 256, 0, stream>>>(attnout, 512, saprojT, sa_proj_b, nullptr,
                                                       fb, nullptr, 512, 512);
    // norm2(f) -> lnb
    ln_k<<<M / 4, 256, 0, stream>>>(fb, n2_g, n2_b, lnb, nullptr);
    // mlp1: hidden = gelu(lnb @ w1 + b1) -> attnout
    gemm_k<4, false, false><<<nM * 4, 256, 0, stream>>>(lnb, 512, mlp1T, mlp_b1, nullptr, nullptr,
                                                        attnout, 512, 512);
    // mlp2: f += hidden @ w2 + b2
    gemm_k<3, false, false><<<nM * 4, 256, 0, stream>>>(attnout, 512, mlp2T, mlp_b2, nullptr, fb,
                                                        nullptr, 512, 512);
    // norm3(f) -> feat (f32 into hb) + lnb
    ln_k<<<M / 4, 256, 0, stream>>>(fb, n3_g, n3_b, lnb, hb);
    // ap1: t = tanh(lnb @ ap_w1 + b1) -> tb
    gemm_k<5, false, false><<<nM * 2, 256, 0, stream>>>(lnb, 512, ap1T, ap_b1, nullptr, nullptr,
                                                        tb, 256, 512);
    // A = t @ ap_w2 + b2
    ap2_k<<<M / 4, 256, 0, stream>>>(tb, ap_w2, ap_b2, Avec);
    // softmax prep
    smprep_k<<<1, 1024, 0, stream>>>(Avec, M, sc);
    // pooled partials
    pool1_k<<<196, 256, 0, stream>>>(Avec, sc, hb, partial);
    // final head
    final_k<<<1, 512, 0, stream>>>(partial, 196, fc2_w, fc2_b, (float*)d_out);
}

// Round 8
// 994.125 us; speedup vs baseline: 1.3865x; 1.2138x over previous
//
#include <hip/hip_runtime.h>
#include <hip/hip_bf16.h>
#include <math.h>

typedef short bf16x8 __attribute__((ext_vector_type(8)));
typedef float f32x4 __attribute__((ext_vector_type(4)));

#define DEV __device__ __forceinline__

DEV ushort f2b(float x) {
    unsigned u = __float_as_uint(x);
    u += 0x7fffu + ((u >> 16) & 1u);
    return (ushort)(u >> 16);
}
DEV float b2f(ushort h) { return __uint_as_float(((unsigned)h) << 16); }
DEV float gelu_f(float x) { return 0.5f * x * (1.0f + erff(x * 0.70710678118654752f)); }

// async global->LDS, 16B per lane; LDS dest wave-uniform base (lane*16 added by HW)
DEV void gl2lds16(const void* g, void* l) {
    __builtin_amdgcn_global_load_lds(
        (const __attribute__((address_space(1))) void*)(uintptr_t)g,
        (__attribute__((address_space(3))) void*)(uintptr_t)l, 16, 0, 0);
}

#define BAR() __builtin_amdgcn_s_barrier()

// ---------------------------------------------------------------------------
// Weight transpose + cast:  Wt[n*K + k] = bf16(W[k*N + n])
// ---------------------------------------------------------------------------
__global__ __launch_bounds__(256) void castT_k(const float* __restrict__ W,
                                               ushort* __restrict__ Wt, int K, int N) {
    long i = (long)blockIdx.x * 256 + threadIdx.x;
    if (i < (long)K * N) {
        int k = (int)(i / N), n = (int)(i % N);
        Wt[(long)n * K + k] = f2b(W[i]);
    }
}

// data[:, 2:1026] f32 -> bf16 [50176][1024]
__global__ __launch_bounds__(256) void dcast_k(const float* __restrict__ data,
                                               ushort* __restrict__ out) {
    long i = ((long)blockIdx.x * 256 + threadIdx.x) * 8;
    int r = (int)(i >> 10);
    int c = (int)(i & 1023);
    const float* p = data + (long)r * 1026 + 2 + c;
    float2 f0 = *(const float2*)p;
    float2 f1 = *(const float2*)(p + 2);
    float2 f2 = *(const float2*)(p + 4);
    float2 f3 = *(const float2*)(p + 6);
    int4 pk;
    pk.x = (int)f2b(f0.x) | ((int)f2b(f0.y) << 16);
    pk.y = (int)f2b(f1.x) | ((int)f2b(f1.y) << 16);
    pk.z = (int)f2b(f2.x) | ((int)f2b(f2.y) << 16);
    pk.w = (int)f2b(f3.x) | ((int)f2b(f3.y) << 16);
    *(int4*)(&out[i]) = pk;
}

// ---------------------------------------------------------------------------
// piecewise_index |.| table for d = 0..511
// ---------------------------------------------------------------------------
__global__ void pw_k(int* __restrict__ pw) {
    int d = threadIdx.x;
    int v;
    if (d == 0) v = 0;
    else if (d <= 3) v = 1;
    else {
        float t = logf((float)d / 1.9f) / 1.7917594692280552f * 3.8f;
        int r = (int)rintf(t);
        v = r < 7 ? r : 7;
    }
    pw[d] = v;
}

// ---------------------------------------------------------------------------
// GEMM: C[M x N] = A[M x K] @ B[K x N] (+bias, epilogues).  A bf16 [M][lda],
// B as Bt[N][K] bf16, out bf16.  BM=BN=128, BK=32, 4 waves, 16x16x32 MFMA.
// K-loop: frozen round-7 structure (3-buffer, counted vmcnt — measured
// neutral but stable/passing).
// NEW: LDS-staged coalesced epilogue — C tile staged bf16 into the dead
// K-loop LDS (granule-XOR swizzle), flat-mapped writeback: each store instr
// covers 4 x 256B contiguous rows. Residual epilogues (2,3) apply at
// writeback from coalesced int4 reads.
// EPI: 0 relu  1 plain  2 gelu(hres+x)  3 out[perm?] += x  4 gelu  5 tanh
// ---------------------------------------------------------------------------
template <int EPI, bool PERMA, bool PERMOUT>
__global__ __launch_bounds__(256, 3) void gemm_k(const ushort* __restrict__ A, long lda,
                                                 const ushort* __restrict__ Bt,
                                                 const float* __restrict__ bias,
                                                 const ushort* __restrict__ hresB,
                                                 ushort* __restrict__ outB, int N, int K) {
    __shared__ ushort sh[3][2][128 * 32];  // 48 KB
    const int tid = threadIdx.x;
    const int nN = N >> 7;
    // bijective XCD-chunk swizzle (m204)
    int nwg = gridDim.x;
    int xcd = blockIdx.x & 7, lin = blockIdx.x >> 3;
    int q = nwg >> 3, r8 = nwg & 7;
    int swz = (xcd < r8 ? xcd * (q + 1) : r8 * (q + 1) + (xcd - r8) * q) + lin;
    const long m0 = (long)(swz / nN) * 128;
    const int n0 = (swz % nN) * 128;
    const int l = tid & 63, wv = tid >> 6;
    const int wm = (wv >> 1) * 64, wn = (wv & 1) * 64;
    const int rr = l & 15, lg = l >> 4;
    const int trow = tid >> 2;                    // row within 64-row chunk
    const int tg = (tid & 3) ^ ((tid >> 3) & 3);  // pre-swizzled source granule

    f32x4 acc[4][4];
#pragma unroll
    for (int a = 0; a < 4; ++a)
#pragma unroll
        for (int b = 0; b < 4; ++b) acc[a][b] = (f32x4){0.f, 0.f, 0.f, 0.f};

    auto stage = [&](int buf, int k0) {
#pragma unroll
        for (int c = 0; c < 2; ++c) {
            int row = c * 64 + trow;
            long arow = m0 + row;
            if (PERMA) {
                int qq = (int)arow / 49;
                int ss = (int)arow - qq * 49;
                arow = (long)ss * 1024 + qq;
            }
            gl2lds16(A + arow * lda + k0 + tg * 8, &sh[buf][0][c * 2048 + wv * 512]);
        }
#pragma unroll
        for (int c = 0; c < 2; ++c) {
            int row = c * 64 + trow;
            gl2lds16(Bt + (long)(n0 + row) * K + k0 + tg * 8, &sh[buf][1][c * 2048 + wv * 512]);
        }
    };

    const int nT = K >> 5;
    stage(0, 0);
    stage(1, 32);
    int cur = 0;  // buffer holding tile t
    int sb = 2;   // buffer for tile t+2

    for (int t = 0; t < nT; ++t) {
        int ahead = nT - 1 - t;
        if (t + 2 < nT) stage(sb, (t + 2) * 32);
        if (ahead >= 2)
            asm volatile("s_waitcnt vmcnt(8)" ::: "memory");
        else if (ahead == 1)
            asm volatile("s_waitcnt vmcnt(4)" ::: "memory");
        else
            asm volatile("s_waitcnt vmcnt(0)" ::: "memory");
        BAR();
        bf16x8 a[4], b[4];
#pragma unroll
        for (int mt = 0; mt < 4; ++mt) {
            int row = wm + mt * 16 + rr;
            int slot = lg ^ ((row >> 1) & 3);
            a[mt] = *(const bf16x8*)(&sh[cur][0][row * 32 + slot * 8]);
        }
#pragma unroll
        for (int nt = 0; nt < 4; ++nt) {
            int row = wn + nt * 16 + rr;
            int slot = lg ^ ((row >> 1) & 3);
            b[nt] = *(const bf16x8*)(&sh[cur][1][row * 32 + slot * 8]);
        }
#pragma unroll
        for (int mt = 0; mt < 4; ++mt)
#pragma unroll
            for (int nt = 0; nt < 4; ++nt)
                acc[mt][nt] =
                    __builtin_amdgcn_mfma_f32_16x16x32_bf16(a[mt], b[nt], acc[mt][nt], 0, 0, 0);
        BAR();
        cur = (cur == 2) ? 0 : cur + 1;
        sb = (sb == 2) ? 0 : sb + 1;
    }

    // ---- LDS-staged coalesced epilogue (LDS dead after final BAR) ----
    ushort* cs = &sh[0][0][0];  // 128x128 bf16 = 32KB
#pragma unroll
    for (int mt = 0; mt < 4; ++mt) {
#pragma unroll
        for (int e = 0; e < 4; ++e) {
            int row = wm + mt * 16 + lg * 4 + e;
#pragma unroll
            for (int nt = 0; nt < 4; ++nt) {
                int col = wn + nt * 16 + rr;
                float v = acc[mt][nt][e] + bias[n0 + col];
                if (EPI == 0) v = fmaxf(v, 0.f);
                else if (EPI == 4) v = gelu_f(v);
                else if (EPI == 5) v = tanhf(v);
                cs[row * 128 + (((col >> 3) ^ (row & 7)) << 3) + (col & 7)] = f2b(v);
            }
        }
    }
    __syncthreads();
#pragma unroll
    for (int i = 0; i < 8; ++i) {
        int row = i * 16 + (tid >> 4);
        int gran = tid & 15;
        long gr = m0 + row;
        long orow = gr;
        if (PERMOUT) {
            int qq = (int)gr / 49;
            int ss = (int)gr - qq * 49;
            orow = (long)ss * 1024 + qq;
        }
        int4 d = *(const int4*)&cs[row * 128 + ((gran ^ (row & 7)) << 3)];
        ushort* po = outB + orow * N + n0 + gran * 8;
        if (EPI == 2 || EPI == 3) {
            const ushort* ph = (EPI == 2) ? (hresB + gr * N + n0 + gran * 8) : po;
            int4 hv = *(const int4*)ph;
            const ushort* dd = (const ushort*)&d;
            const ushort* hh = (const ushort*)&hv;
            int4 r;
            ushort* ro = (ushort*)&r;
#pragma unroll
            for (int j = 0; j < 8; ++j) {
                float x = b2f(hh[j]) + b2f(dd[j]);
                if (EPI == 2) x = gelu_f(x);
                ro[j] = f2b(x);
            }
            *(int4*)po = r;
        } else {
            *(int4*)po = d;
        }
    }
}

// ---------------------------------------------------------------------------
// LayerNorm over bf16 rows of 512 -> bf16. 256 thr = 4 waves, 1 row per wave.
// ---------------------------------------------------------------------------
__global__ __launch_bounds__(256) void ln_k(const ushort* __restrict__ x,
                                            const float* __restrict__ g,
                                            const float* __restrict__ b,
                                            ushort* __restrict__ outB) {
    long row = (long)blockIdx.x * 4 + (threadIdx.x >> 6);
    int l = threadIdx.x & 63;
    int4 u = *(const int4*)(x + row * 512 + l * 8);
    const ushort* us = (const ushort*)&u;
    float xv[8];
    float s = 0.f, qs = 0.f;
#pragma unroll
    for (int j = 0; j < 8; ++j) {
        xv[j] = b2f(us[j]);
        s += xv[j];
        qs += xv[j] * xv[j];
    }
#pragma unroll
    for (int m = 1; m < 64; m <<= 1) {
        s += __shfl_xor(s, m);
        qs += __shfl_xor(qs, m);
    }
    float mean = s * (1.f / 512.f);
    float var = qs * (1.f / 512.f) - mean * mean;
    float rstd = rsqrtf(var + 1e-5f);
    float4 g0 = *(const float4*)(g + l * 8);
    float4 g1 = *(const float4*)(g + l * 8 + 4);
    float4 b0 = *(const float4*)(b + l * 8);
    float4 b1 = *(const float4*)(b + l * 8 + 4);
    float gg[8] = {g0.x, g0.y, g0.z, g0.w, g1.x, g1.y, g1.z, g1.w};
    float bb[8] = {b0.x, b0.y, b0.z, b0.w, b1.x, b1.y, b1.z, b1.w};
    int4 pk;
    ushort* po = (ushort*)&pk;
#pragma unroll
    for (int j = 0; j < 8; ++j) po[j] = f2b((xv[j] - mean) * rstd * gg[j] + bb[j]);
    *(int4*)(&outB[row * 512 + l * 8]) = pk;
}

// ---------------------------------------------------------------------------
// Fused per-(window,head) attention. 1 wave/block, 49 tokens padded to 64.
// Q,K fragments direct from qkv; V transposed in-LDS (round-2 pattern,
// zero-padded). P through LDS. s_setprio around MFMA clusters (T5).
// ---------------------------------------------------------------------------
template <bool BIAS>
__global__ __launch_bounds__(64) void attn_k(const ushort* __restrict__ qkv,
                                             const float* __restrict__ cdata,
                                             const int* __restrict__ pwt,
                                             const float* __restrict__ btg,
                                             ushort* __restrict__ outb) {
    __shared__ ushort vt[4096];
    __shared__ ushort ps[4096];
    __shared__ float cx[64], cy[64], bt[16];
    __shared__ unsigned char pwu[512];

    const int l = threadIdx.x;
    const int w = blockIdx.x >> 3, hh = blockIdx.x & 7;
    const long rowbase = (long)w * 49;
    const int rr = l & 15, lg = l >> 4;

    // V stage + transpose into vt (zero-padded tokens >= 49)
    for (int idx = l; idx < 512; idx += 64) {
        int t = idx >> 3, g = idx & 7;
        int4 zv = make_int4(0, 0, 0, 0);
        if (t < 49) zv = *(const int4*)(qkv + (rowbase + t) * 1536 + 1024 + hh * 64 + g * 8);
        ushort* pv = (ushort*)&zv;
#pragma unroll
        for (int ii = 0; ii < 8; ++ii) {
            int d = g * 8 + ii;
            vt[d * 64 + (((t >> 3) ^ ii) * 8) + (t & 7)] = pv[ii];
        }
    }
    if (BIAS) {
        if (l < 49) {
            cx[l] = cdata[(rowbase + l) * 1026];
            cy[l] = cdata[(rowbase + l) * 1026 + 1];
        }
        if (l < 15) bt[l] = btg[l * 8 + hh];
        for (int i = l; i < 512; i += 64) pwu[i] = (unsigned char)pwt[i];
    }

    // QK^T: direct global fragment loads
    f32x4 s[4][4];
#pragma unroll
    for (int a = 0; a < 4; ++a)
#pragma unroll
        for (int b = 0; b < 4; ++b) s[a][b] = (f32x4){0.f, 0.f, 0.f, 0.f};

    const bf16x8 zfrag = {0, 0, 0, 0, 0, 0, 0, 0};
#pragma unroll
    for (int kk = 0; kk < 2; ++kk) {
        bf16x8 a[4], b[4];
#pragma unroll
        for (int mt = 0; mt < 4; ++mt) {
            int i = mt * 16 + rr;
            a[mt] = (i < 49) ? *(const bf16x8*)(qkv + (rowbase + i) * 1536 + hh * 64 +
                                                (kk * 4 + lg) * 8)
                             : zfrag;
        }
#pragma unroll
        for (int nt = 0; nt < 4; ++nt) {
            int j = nt * 16 + rr;
            b[nt] = (j < 49) ? *(const bf16x8*)(qkv + (rowbase + j) * 1536 + 512 + hh * 64 +
                                                (kk * 4 + lg) * 8)
                             : zfrag;
        }
        __builtin_amdgcn_s_setprio(1);
#pragma unroll
        for (int mt = 0; mt < 4; ++mt)
#pragma unroll
            for (int nt = 0; nt < 4; ++nt)
                s[mt][nt] = __builtin_amdgcn_mfma_f32_16x16x32_bf16(a[mt], b[nt], s[mt][nt], 0, 0, 0);
        __builtin_amdgcn_s_setprio(0);
    }
    __syncthreads();

    // scale + bias + padding mask; batched softmax reductions (ILP)
    float mrow[16], srow[16];
#pragma unroll
    for (int mt = 0; mt < 4; ++mt) {
#pragma unroll
        for (int e = 0; e < 4; ++e) {
            int i = mt * 16 + lg * 4 + e;
            float mloc = -1e30f;
#pragma unroll
            for (int nt = 0; nt < 4; ++nt) {
                int j = nt * 16 + rr;
                float v = s[mt][nt][e] * 0.125f;
                if (j >= 49) {
                    v = -1e30f;
                } else if (BIAS) {
                    if (i < 49) {
                        int dx = (int)fabsf(cx[i] - cx[j]);
                        int dy = (int)fabsf(cy[i] - cy[j]);
                        v += bt[pwu[dx] + pwu[dy]];
                    }
                }
                s[mt][nt][e] = v;
                mloc = fmaxf(mloc, v);
            }
            mrow[mt * 4 + e] = mloc;
        }
    }
#pragma unroll
    for (int msk = 1; msk < 16; msk <<= 1)
#pragma unroll
        for (int r = 0; r < 16; ++r) mrow[r] = fmaxf(mrow[r], __shfl_xor(mrow[r], msk));
#pragma unroll
    for (int mt = 0; mt < 4; ++mt) {
#pragma unroll
        for (int e = 0; e < 4; ++e) {
            int r = mt * 4 + e;
            int i = mt * 16 + lg * 4 + e;
            float sm = 0.f;
#pragma unroll
            for (int nt = 0; nt < 4; ++nt) {
                int j = nt * 16 + rr;
                float p = __expf(s[mt][nt][e] - mrow[r]);
                sm += p;
                ps[i * 64 + (((j >> 3) ^ (i & 7)) * 8) + (j & 7)] = f2b(p);
            }
            srow[r] = sm;
        }
    }
#pragma unroll
    for (int msk = 1; msk < 16; msk <<= 1)
#pragma unroll
        for (int r = 0; r < 16; ++r) srow[r] += __shfl_xor(srow[r], msk);
#pragma unroll
    for (int r = 0; r < 16; ++r) srow[r] = 1.f / srow[r];
    __syncthreads();

    f32x4 o[4][4];
#pragma unroll
    for (int a = 0; a < 4; ++a)
#pragma unroll
        for (int b = 0; b < 4; ++b) o[a][b] = (f32x4){0.f, 0.f, 0.f, 0.f};

#pragma unroll
    for (int kk = 0; kk < 2; ++kk) {
        bf16x8 a[4], b[4];
#pragma unroll
        for (int mt = 0; mt < 4; ++mt) {
            int i = mt * 16 + rr;
            int slot = (kk * 4 + lg) ^ (i & 7);
            a[mt] = *(const bf16x8*)(&ps[i * 64 + slot * 8]);
        }
#pragma unroll
        for (int nt = 0; nt < 4; ++nt) {
            int d = nt * 16 + rr;
            int slot = (kk * 4 + lg) ^ (d & 7);
            b[nt] = *(const bf16x8*)(&vt[d * 64 + slot * 8]);
        }
        __builtin_amdgcn_s_setprio(1);
#pragma unroll
        for (int mt = 0; mt < 4; ++mt)
#pragma unroll
            for (int nt = 0; nt < 4; ++nt)
                o[mt][nt] = __builtin_amdgcn_mfma_f32_16x16x32_bf16(a[mt], b[nt], o[mt][nt], 0, 0, 0);
        __builtin_amdgcn_s_setprio(0);
    }

#pragma unroll
    for (int mt = 0; mt < 4; ++mt) {
#pragma unroll
        for (int e = 0; e < 4; ++e) {
            int i = mt * 16 + lg * 4 + e;
            if (i < 49) {
#pragma unroll
                for (int nt = 0; nt < 4; ++nt) {
                    int col = hh * 64 + nt * 16 + rr;
                    outb[(rowbase + i) * 512 + col] = f2b(o[mt][nt][e] * srow[mt * 4 + e]);
                }
            }
        }
    }
}

// ---------------------------------------------------------------------------
// A[r] = tanh_t[r,:256] . ap_w2 + ap_b2     (one wave per row)
// ---------------------------------------------------------------------------
__global__ __launch_bounds__(256) void ap2_k(const ushort* __restrict__ tb,
                                             const float* __restrict__ w2,
                                             const float* __restrict__ b2,
                                             float* __restrict__ Avec) {
    long row = (long)blockIdx.x * 4 + (threadIdx.x >> 6);
    int l = threadIdx.x & 63;
    ushort4 u = *(const ushort4*)(tb + row * 256 + l * 4);
    float4 wv = *(const float4*)(w2 + l * 4);
    float s = b2f(u.x) * wv.x + b2f(u.y) * wv.y + b2f(u.z) * wv.z + b2f(u.w) * wv.w;
#pragma unroll
    for (int m = 1; m < 64; m <<= 1) s += __shfl_xor(s, m);
    if (l == 0) Avec[row] = s + b2[0];
}

__global__ __launch_bounds__(1024) void smprep_k(const float* __restrict__ A, int M,
                                                 float* __restrict__ sc) {
    __shared__ float red[1024];
    int t = threadIdx.x;
    float m = -3.4e38f;
    for (int i = t; i < M; i += 1024) m = fmaxf(m, A[i]);
    red[t] = m;
    __syncthreads();
    for (int o = 512; o > 0; o >>= 1) {
        if (t < o) red[t] = fmaxf(red[t], red[t + o]);
        __syncthreads();
    }
    float mx = red[0];
    __syncthreads();
    float s = 0.f;
    for (int i = t; i < M; i += 1024) s += __expf(A[i] - mx);
    red[t] = s;
    __syncthreads();
    for (int o = 512; o > 0; o >>= 1) {
        if (t < o) red[t] += red[t + o];
        __syncthreads();
    }
    if (t == 0) {
        sc[0] = mx;
        sc[1] = red[0];
    }
}

__global__ __launch_bounds__(256) void pool1_k(const float* __restrict__ Avec,
                                               const float* __restrict__ sc,
                                               const ushort* __restrict__ feat,
                                               float* __restrict__ partial) {
    int t = threadIdx.x;
    long base = (long)blockIdx.x * 256;
    float mx = sc[0], rd = 1.f / sc[1];
    float a0 = 0.f, a1 = 0.f;
    for (int i = 0; i < 256; ++i) {
        long tok = base + i;
        float wt = __expf(Avec[tok] - mx) * rd;
        a0 += wt * b2f(feat[tok * 512 + t]);
        a1 += wt * b2f(feat[tok * 512 + t + 256]);
    }
    partial[(long)blockIdx.x * 512 + t] = a0;
    partial[(long)blockIdx.x * 512 + t + 256] = a1;
}

__global__ __launch_bounds__(512) void final_k(const float* __restrict__ partial, int NP,
                                               const float* __restrict__ fc2w,
                                               const float* __restrict__ fc2b,
                                               float* __restrict__ out) {
    __shared__ float pooled[512];
    __shared__ float lgs[4];
    int t = threadIdx.x;
    float s = 0.f;
    for (int b = 0; b < NP; ++b) s += partial[(long)b * 512 + t];
    pooled[t] = s;
    __syncthreads();
    if (t < 4) {
        float x = fc2b[t];
        for (int c = 0; c < 512; ++c) x += pooled[c] * fc2w[c * 4 + t];
        lgs[t] = x;
    }
    __syncthreads();
    if (t == 0) {
        float hz[4];
        for (int i = 0; i < 4; ++i) hz[i] = 1.f / (1.f + __expf(-lgs[i]));
        for (int i = 0; i < 4; ++i) out[i] = hz[i];
        float cp = 1.f;
        for (int i = 0; i < 4; ++i) {
            cp *= (1.f - hz[i]);
            out[4 + i] = cp;
        }
        int best = 0;
        for (int i = 1; i < 4; ++i)
            if (lgs[i] > lgs[best]) best = i;
        out[8] = (float)best;
    }
}

// ---------------------------------------------------------------------------
extern "C" void kernel_launch(void* const* d_in, const int* in_sizes, int n_in, void* d_out,
                              int out_size, void* d_ws, size_t ws_size, hipStream_t stream) {
    const float* data = (const float*)d_in[0];
    const float* fc1_w = (const float*)d_in[1];
    const float* fc1_b = (const float*)d_in[2];
    const float* ln1_g = (const float*)d_in[3];
    const float* ln1_b = (const float*)d_in[4];
    const float* wa_qkv_w = (const float*)d_in[5];
    const float* wa_qkv_b = (const float*)d_in[6];
    const float* wa_bt = (const float*)d_in[7];
    const float* wa_proj_w = (const float*)d_in[8];
    const float* wa_proj_b = (const float*)d_in[9];
    const float* n1_g = (const float*)d_in[10];
    const float* n1_b = (const float*)d_in[11];
    const float* sa_qkv_w = (const float*)d_in[12];
    const float* sa_qkv_b = (const float*)d_in[13];
    const float* sa_proj_w = (const float*)d_in[14];
    const float* sa_proj_b = (const float*)d_in[15];
    const float* n2_g = (const float*)d_in[16];
    const float* n2_b = (const float*)d_in[17];
    const float* mlp_w1 = (const float*)d_in[18];
    const float* mlp_b1 = (const float*)d_in[19];
    const float* mlp_w2 = (const float*)d_in[20];
    const float* mlp_b2 = (const float*)d_in[21];
    const float* n3_g = (const float*)d_in[22];
    const float* n3_b = (const float*)d_in[23];
    const float* ap_w1 = (const float*)d_in[24];
    const float* ap_b1 = (const float*)d_in[25];
    const float* ap_w2 = (const float*)d_in[26];
    const float* ap_b2 = (const float*)d_in[27];
    const float* fc2_w = (const float*)d_in[28];
    const float* fc2_b = (const float*)d_in[29];

    const int M = 50176;  // tokens
    const int nM = M / 128;

    char* ws = (char*)d_ws;
    size_t off = 0;
    auto alloc = [&](size_t bytes) {
        size_t p = off;
        off = (off + bytes + 255) & ~(size_t)255;
        return (void*)(ws + p);
    };

    ushort* fc1T = (ushort*)alloc((size_t)512 * 1024 * 2);
    ushort* waqkvT = (ushort*)alloc((size_t)1536 * 512 * 2);
    ushort* waprojT = (ushort*)alloc((size_t)512 * 512 * 2);
    ushort* saqkvT = (ushort*)alloc((size_t)1536 * 512 * 2);
    ushort* saprojT = (ushort*)alloc((size_t)512 * 512 * 2);
    ushort* mlp1T = (ushort*)alloc((size_t)512 * 512 * 2);
    ushort* mlp2T = (ushort*)alloc((size_t)512 * 512 * 2);
    ushort* ap1T = (ushort*)alloc((size_t)256 * 512 * 2);
    int* pwtab = (int*)alloc(512 * 4);
    float* sc = (float*)alloc(64);
    float* Avec = (float*)alloc((size_t)M * 4);
    float* partial = (float*)alloc((size_t)196 * 512 * 4);
    ushort* hbB = (ushort*)alloc((size_t)M * 512 * 2);     // h (bf16)
    ushort* fbB = (ushort*)alloc((size_t)M * 512 * 2);     // f (bf16)
    ushort* lnb = (ushort*)alloc((size_t)M * 512 * 2);     // LN output (bf16)
    ushort* attnout = (ushort*)alloc((size_t)M * 512 * 2);
    ushort* qkvb = (ushort*)alloc((size_t)M * 1536 * 2);
    ushort* dataB = qkvb;  // [M][1024] bf16, dead once WA qkv runs
    ushort* tb = qkvb;     // tanh output (M x 256), after SA attn done

    // weight transposes + casts + tables
    castT_k<<<(512 * 1024 + 255) / 256, 256, 0, stream>>>(fc1_w, fc1T, 1024, 512);
    castT_k<<<(512 * 1536 + 255) / 256, 256, 0, stream>>>(wa_qkv_w, waqkvT, 512, 1536);
    castT_k<<<(512 * 512 + 255) / 256, 256, 0, stream>>>(wa_proj_w, waprojT, 512, 512);
    castT_k<<<(512 * 1536 + 255) / 256, 256, 0, stream>>>(sa_qkv_w, saqkvT, 512, 1536);
    castT_k<<<(512 * 512 + 255) / 256, 256, 0, stream>>>(sa_proj_w, saprojT, 512, 512);
    castT_k<<<(512 * 512 + 255) / 256, 256, 0, stream>>>(mlp_w1, mlp1T, 512, 512);
    castT_k<<<(512 * 512 + 255) / 256, 256, 0, stream>>>(mlp_w2, mlp2T, 512, 512);
    castT_k<<<(256 * 512 + 255) / 256, 256, 0, stream>>>(ap_w1, ap1T, 512, 256);
    pw_k<<<1, 512, 0, stream>>>(pwtab);
    dcast_k<<<25088, 256, 0, stream>>>(data, dataB);

    // fc1 + relu -> h (bf16)
    gemm_k<0, false, false><<<nM * 4, 256, 0, stream>>>(dataB, 1024, fc1T, fc1_b, nullptr, hbB,
                                                        512, 1024);
    // ln1(h) -> lnb
    ln_k<<<M / 4, 256, 0, stream>>>(hbB, ln1_g, ln1_b, lnb);
    // WA qkv
    gemm_k<1, false, false><<<nM * 12, 256, 0, stream>>>(lnb, 512, waqkvT, wa_qkv_b, nullptr,
                                                         qkvb, 1536, 512);
    // WA attention (with bias)
    attn_k<true><<<8192, 64, 0, stream>>>(qkvb, data, pwtab, wa_bt, attnout);
    // WA proj: f = gelu(h + out)  (bf16)
    gemm_k<2, false, false><<<nM * 4, 256, 0, stream>>>(attnout, 512, waprojT, wa_proj_b, hbB,
                                                        fbB, 512, 512);
    // norm1(f) -> lnb
    ln_k<<<M / 4, 256, 0, stream>>>(fbB, n1_g, n1_b, lnb);
    // SA qkv (permuted gather of A rows)
    gemm_k<1, true, false><<<nM * 12, 256, 0, stream>>>(lnb, 512, saqkvT, sa_qkv_b, nullptr,
                                                        qkvb, 1536, 512);
    // SA attention (no bias)
    attn_k<false><<<8192, 64, 0, stream>>>(qkvb, nullptr, nullptr, nullptr, attnout);
    // SA proj: f[perm] += out
    gemm_k<3, false, true><<<nM * 4, 256, 0, stream>>>(attnout, 512, saprojT, sa_proj_b, nullptr,
                                                       fbB, 512, 512);
    // norm2(f) -> lnb
    ln_k<<<M / 4, 256, 0, stream>>>(fbB, n2_g, n2_b, lnb);
    // mlp1: hidden = gelu(lnb @ w1 + b1) -> attnout
    gemm_k<4, false, false><<<nM * 4, 256, 0, stream>>>(lnb, 512, mlp1T, mlp_b1, nullptr, attnout,
                                                        512, 512);
    // mlp2: f += hidden @ w2 + b2
    gemm_k<3, false, false><<<nM * 4, 256, 0, stream>>>(attnout, 512, mlp2T, mlp_b2, nullptr, fbB,
                                                        512, 512);
    // norm3(f) -> lnb (feat for ap1 AND pooling)
    ln_k<<<M / 4, 256, 0, stream>>>(fbB, n3_g, n3_b, lnb);
    // ap1: t = tanh(lnb @ ap_w1 + b1) -> tb
    gemm_k<5, false, false><<<nM * 2, 256, 0, stream>>>(lnb, 512, ap1T, ap_b1, nullptr, tb, 256,
                                                        512);
    // A = t @ ap_w2 + b2
    ap2_k<<<M / 4, 256, 0, stream>>>(tb, ap_w2, ap_b2, Avec);
    // softmax prep
    smprep_k<<<1, 1024, 0, stream>>>(Avec, M, sc);
    // pooled partials (feat = lnb, bf16)
    pool1_k<<<196, 256, 0, stream>>>(Avec, sc, lnb, partial);
    // final head
    final_k<<<1, 512, 0, stream>>>(partial, 196, fc2_w, fc2_b, (float*)d_out);
}